// Round 2
// baseline (3051.446 us; speedup 1.0000x reference)
//
#include <hip/hip_runtime.h>

#define N_NODES 50000
#define N_EDGES 800000
#define N_GRAPHS 256

#define BM 64
#define BK 32
#define SA 36    // lds_a row stride (floats): 144B, 16B-aligned
#define SB 144   // lds_b row stride (floats): 576B, 16B-aligned

// ---------------------------------------------------------------------------
// Fused GEMM: C[m][c] = act( sum_k A0[m][k]*B0[c][k] (+ A1@B1) + bias )
//  - NSPLIT=false: K-concat  (layers 1,2): C = tanh(A0@B0^T + A1@B1^T + bias)
//  - NSPLIT=true : N-concat  (layer 3):    C[:, :64] = A0@B0^T,
//                                          C[:,64:] = A0@B1^T + bias
// B matrices are [128 or 64][KPER] row-major (PyTorch lin weight layout).
// ---------------------------------------------------------------------------
template<int KPER, bool NSPLIT, bool ACT>
__global__ __launch_bounds__(256)
void gemm_fused(const float* __restrict__ A0, const float* __restrict__ A1,
                const float* __restrict__ B0, const float* __restrict__ B1,
                const float* __restrict__ bias, float* __restrict__ C)
{
    __shared__ float lds_a[BM * SA];
    __shared__ float lds_b[BK * SB];

    const int tid = threadIdx.x;
    const int tm = tid >> 4;       // 0..15 -> rows tm*4 .. tm*4+3
    const int tn = tid & 15;       // 0..15 -> cols tn*8 .. tn*8+7
    const int m0 = blockIdx.x * BM;

    constexpr int NCH_PER = KPER / BK;
    constexpr int NCH = NSPLIT ? NCH_PER : 2 * NCH_PER;

    float acc[4][8] = {};

    // swizzled LDS column offset for this thread's 8 columns
    const int boff = tn * 8 + (tn >> 2) * 4;

    for (int ch = 0; ch < NCH; ++ch) {
        const int k0 = (ch % NCH_PER) * BK;
        const bool first = NSPLIT || (ch < NCH_PER);
        const float* __restrict__ Asel = first ? A0 : A1;
        const float* __restrict__ Bsel = first ? B0 : B1;

        __syncthreads();
        // ---- stage A tile: 64 x 32 floats ----
#pragma unroll
        for (int q = tid; q < BM * BK / 4; q += 256) {
            const int r  = q >> 3;
            const int kq = (q & 7) * 4;
            int row = m0 + r; if (row >= N_NODES) row = N_NODES - 1;
            const float4 v = *(const float4*)&Asel[(long)row * KPER + k0 + kq];
            *(float4*)&lds_a[r * SA + kq] = v;
        }
        // ---- stage B tile transposed+swizzled: 128 x 32 floats ----
#pragma unroll
        for (int q = tid; q < 128 * BK / 4; q += 256) {
            const int c  = q >> 3;
            const int kq = (q & 7) * 4;
            const float* brow;
            if (NSPLIT) brow = (c < 64) ? (B0 + (long)c * KPER)
                                        : (B1 + (long)(c - 64) * KPER);
            else        brow = Bsel + (long)c * KPER;
            const float4 v = *(const float4*)&brow[k0 + kq];
            const int g = c >> 3;
            const int cp = g * 8 + (g >> 2) * 4 + (c & 7);
            lds_b[(kq + 0) * SB + cp] = v.x;
            lds_b[(kq + 1) * SB + cp] = v.y;
            lds_b[(kq + 2) * SB + cp] = v.z;
            lds_b[(kq + 3) * SB + cp] = v.w;
        }
        __syncthreads();

#pragma unroll 2
        for (int kk = 0; kk < BK; kk += 4) {
            float4 af[4];
#pragma unroll
            for (int i = 0; i < 4; ++i)
                af[i] = *(const float4*)&lds_a[(tm * 4 + i) * SA + kk];
#pragma unroll
            for (int j = 0; j < 4; ++j) {
                const float4 b0 = *(const float4*)&lds_b[(kk + j) * SB + boff];
                const float4 b1 = *(const float4*)&lds_b[(kk + j) * SB + boff + 4];
                const float bb[8] = {b0.x, b0.y, b0.z, b0.w, b1.x, b1.y, b1.z, b1.w};
#pragma unroll
                for (int i = 0; i < 4; ++i) {
                    const float a = (&af[i].x)[j];
#pragma unroll
                    for (int n = 0; n < 8; ++n)
                        acc[i][n] = fmaf(a, bb[n], acc[i][n]);
                }
            }
        }
    }

    // ---- epilogue: bias + activation + store ----
#pragma unroll
    for (int i = 0; i < 4; ++i) {
        const int m = m0 + tm * 4 + i;
        if (m >= N_NODES) break;
        float out[8];
#pragma unroll
        for (int n = 0; n < 8; ++n) {
            const int c = tn * 8 + n;
            const float b = NSPLIT ? (c < 64 ? 0.f : bias[c - 64]) : bias[c];
            const float v = acc[i][n] + b;
            out[n] = ACT ? tanhf(v) : v;
        }
        *(float4*)&C[(long)m * 128 + tn * 8]     = make_float4(out[0], out[1], out[2], out[3]);
        *(float4*)&C[(long)m * 128 + tn * 8 + 4] = make_float4(out[4], out[5], out[6], out[7]);
    }
}

// ---------------------------------------------------------------------------
// scatter (float4): agg[dst][j..j+3] += src[src][j..j+3] * w
// ---------------------------------------------------------------------------
__global__ void scatter4_kernel(const float* __restrict__ src_data, int src_stride,
                                const int* __restrict__ ei, const float* __restrict__ ew,
                                float* __restrict__ agg, int d, int d4log)
{
    const int d4 = 1 << d4log;
    const long total = (long)N_EDGES << d4log;
    const long gsz = (long)gridDim.x * blockDim.x;
    for (long i = (long)blockIdx.x * blockDim.x + threadIdx.x; i < total; i += gsz) {
        const int e = (int)(i >> d4log);
        const int j = (int)(i & (d4 - 1)) << 2;
        const int s = ei[e];
        const int t = ei[N_EDGES + e];
        const float w = ew[e];
        const float4 v = *(const float4*)&src_data[(long)s * src_stride + j];
        float* dst = &agg[(long)t * d + j];
        atomicAdd(dst + 0, v.x * w);
        atomicAdd(dst + 1, v.y * w);
        atomicAdd(dst + 2, v.z * w);
        atomicAdd(dst + 3, v.w * w);
    }
}

// ---------------------------------------------------------------------------
// h3 = tanh(agg3 + r3); pool: g[batch[n]][c] += h3[n][c]   (float4)
// ---------------------------------------------------------------------------
__global__ void pool_kernel(const float* __restrict__ agg3, const float* __restrict__ yr,
                            const int* __restrict__ batch, float* __restrict__ g)
{
    const long total = (long)N_NODES * 16;
    const long gsz = (long)gridDim.x * blockDim.x;
    for (long i = (long)blockIdx.x * blockDim.x + threadIdx.x; i < total; i += gsz) {
        const int n = (int)(i >> 4);
        const int c = (int)(i & 15) << 2;
        const float4 a = *(const float4*)&agg3[(long)n * 64 + c];
        const float4 r = *(const float4*)&yr[(long)n * 128 + 64 + c];
        float* dst = &g[batch[n] * 64 + c];
        atomicAdd(dst + 0, tanhf(a.x + r.x));
        atomicAdd(dst + 1, tanhf(a.y + r.y));
        atomicAdd(dst + 2, tanhf(a.z + r.z));
        atomicAdd(dst + 3, tanhf(a.w + r.w));
    }
}

// ---------------------------------------------------------------------------
// tiny MLP: 64 -> 32 -> 16 -> 1 per graph; one thread per graph
// ---------------------------------------------------------------------------
__global__ void mlp_kernel(const float* __restrict__ g,
                           const float* __restrict__ Wm1, const float* __restrict__ bm1,
                           const float* __restrict__ Wm2, const float* __restrict__ bm2,
                           const float* __restrict__ Wm3, const float* __restrict__ bm3,
                           float* __restrict__ out)
{
    const int gi = blockIdx.x * blockDim.x + threadIdx.x;
    if (gi >= N_GRAPHS) return;
    const float* gr = g + gi * 64;
    float h1[32];
#pragma unroll
    for (int j = 0; j < 32; ++j) {
        float a = bm1[j];
        const float* w = Wm1 + j * 64;
        for (int k = 0; k < 64; ++k) a = fmaf(gr[k], w[k], a);
        h1[j] = fmaxf(a, 0.f);
    }
    float h2[16];
#pragma unroll
    for (int j = 0; j < 16; ++j) {
        float a = bm2[j];
        const float* w = Wm2 + j * 32;
        for (int k = 0; k < 32; ++k) a = fmaf(h1[k], w[k], a);
        h2[j] = fmaxf(a, 0.f);
    }
    float a = bm3[0];
    for (int k = 0; k < 16; ++k) a = fmaf(h2[k], Wm3[k], a);
    out[gi] = a;
}

extern "C" void kernel_launch(void* const* d_in, const int* in_sizes, int n_in,
                              void* d_out, int out_size, void* d_ws, size_t ws_size,
                              hipStream_t stream) {
    const float* x      = (const float*)d_in[0];
    const int*   ei     = (const int*)  d_in[1];
    const int*   batch  = (const int*)  d_in[2];
    const float* ew     = (const float*)d_in[3];
    const float* W1r    = (const float*)d_in[4];
    const float* b1     = (const float*)d_in[5];
    const float* W1root = (const float*)d_in[6];
    const float* W2r    = (const float*)d_in[7];
    const float* b2     = (const float*)d_in[8];
    const float* W2root = (const float*)d_in[9];
    const float* W3r    = (const float*)d_in[10];
    const float* b3     = (const float*)d_in[11];
    const float* W3root = (const float*)d_in[12];
    const float* Wm1    = (const float*)d_in[13];
    const float* bm1    = (const float*)d_in[14];
    const float* Wm2    = (const float*)d_in[15];
    const float* bm2    = (const float*)d_in[16];
    const float* Wm3    = (const float*)d_in[17];
    const float* bm3    = (const float*)d_in[18];
    float* out = (float*)d_out;

    float* P0   = (float*)d_ws;                 // N*128 floats
    float* P1   = P0 + (long)N_NODES * 128;     // N*128 floats
    float* P2   = P1 + (long)N_NODES * 128;     // N*128 floats
    float* POOL = P2 + (long)N_NODES * 128;     // 256*64 floats

    const int gemm_grid = (N_NODES + BM - 1) / BM;   // 782

    // ---- layer 1: agg1 (N x 64) in P0; h1 = tanh([agg1|x]@[W1r|W1root]^T+b1) in P1
    hipMemsetAsync(P0, 0, (size_t)N_NODES * 64 * sizeof(float), stream);
    scatter4_kernel<<<2048, 256, 0, stream>>>(x, 64, ei, ew, P0, 64, 4);
    gemm_fused<64, false, true><<<gemm_grid, 256, 0, stream>>>(P0, x, W1r, W1root, b1, P1);

    // ---- layer 2: agg2 (N x 128) in P2; h2 in P0
    hipMemsetAsync(P2, 0, (size_t)N_NODES * 128 * sizeof(float), stream);
    scatter4_kernel<<<2048, 256, 0, stream>>>(P1, 128, ei, ew, P2, 128, 5);
    gemm_fused<128, false, true><<<gemm_grid, 256, 0, stream>>>(P2, P1, W2r, W2root, b2, P0);

    // ---- layer 3: yr (N x 128: [y3 | root3+b3]) in P1; agg3 (N x 64) in P2
    gemm_fused<128, true, false><<<gemm_grid, 256, 0, stream>>>(P0, P0, W3r, W3root, b3, P1);
    hipMemsetAsync(P2, 0, (size_t)N_NODES * 64 * sizeof(float), stream);
    scatter4_kernel<<<2048, 256, 0, stream>>>(P1, 128, ei, ew, P2, 64, 4);

    // ---- pool + MLP ----
    hipMemsetAsync(POOL, 0, (size_t)N_GRAPHS * 64 * sizeof(float), stream);
    pool_kernel<<<2048, 256, 0, stream>>>(P2, P1, batch, POOL);
    mlp_kernel<<<1, 256, 0, stream>>>(POOL, Wm1, bm1, Wm2, bm2, Wm3, bm3, out);
}

// Round 3
// 529.431 us; speedup vs baseline: 5.7636x; 5.7636x over previous
//
#include <hip/hip_runtime.h>

#define N_NODES 50000
#define N_EDGES 800000
#define N_GRAPHS 256

#define BM 64
#define BK 32
#define SA 36    // lds_a row stride (floats)
#define SB 144   // lds_b row stride (floats)

// ---------------------------------------------------------------------------
// CSR build: count -> scan -> fill   (edges grouped by dst, reused 3x)
// ---------------------------------------------------------------------------
__global__ void count_kernel(const int* __restrict__ ei, int* __restrict__ count)
{
    const int e = blockIdx.x * blockDim.x + threadIdx.x;
    if (e < N_EDGES) atomicAdd(&count[ei[N_EDGES + e]], 1);
}

__global__ __launch_bounds__(1024)
void scan_kernel(const int* __restrict__ count, int* __restrict__ offsets,
                 int* __restrict__ cursor)
{
    __shared__ int psum[1024];
    const int tid = threadIdx.x;
    const int lo = tid * 49;
    const int hi = min(lo + 49, N_NODES);
    int s = 0;
    for (int i = lo; i < hi; ++i) s += count[i];
    psum[tid] = s;
    __syncthreads();
    for (int d = 1; d < 1024; d <<= 1) {
        int v = (tid >= d) ? psum[tid - d] : 0;
        __syncthreads();
        psum[tid] += v;
        __syncthreads();
    }
    int base = (tid == 0) ? 0 : psum[tid - 1];
    for (int i = lo; i < hi; ++i) {
        offsets[i] = base; cursor[i] = base; base += count[i];
    }
    if (tid == 1023) offsets[N_NODES] = N_EDGES;
}

__global__ void fill_kernel(const int* __restrict__ ei, const float* __restrict__ ew,
                            int* __restrict__ cursor,
                            int* __restrict__ esrc, float* __restrict__ ewt)
{
    const int e = blockIdx.x * blockDim.x + threadIdx.x;
    if (e >= N_EDGES) return;
    const int t = ei[N_EDGES + e];
    const int pos = atomicAdd(&cursor[t], 1);
    esrc[pos] = ei[e];
    ewt[pos]  = ew[e];
}

// ---------------------------------------------------------------------------
// gather aggregation: agg[n][:] = sum_{e in csr[n]} ewt[e] * feat[esrc[e]][:]
// D/4 lanes per node, float4 per lane, register accumulate. No atomics.
// ---------------------------------------------------------------------------
template<int D>
__global__ __launch_bounds__(256)
void gather_agg(const float* __restrict__ feat, int stride,
                const int* __restrict__ offsets, const int* __restrict__ esrc,
                const float* __restrict__ ewt, float* __restrict__ agg)
{
    constexpr int LPN = D / 4;       // lanes per node
    constexpr int NPB = 256 / LPN;   // nodes per block
    const int lane = threadIdx.x % LPN;
    const int slot = threadIdx.x / LPN;
    const int n = blockIdx.x * NPB + slot;
    if (n >= N_NODES) return;
    const int lo = offsets[n], hi = offsets[n + 1];
    const int j = lane * 4;
    float4 acc = make_float4(0.f, 0.f, 0.f, 0.f);
    for (int e = lo; e < hi; ++e) {
        const int s = esrc[e];
        const float w = ewt[e];
        const float4 v = *(const float4*)&feat[(long)s * stride + j];
        acc.x = fmaf(v.x, w, acc.x);
        acc.y = fmaf(v.y, w, acc.y);
        acc.z = fmaf(v.z, w, acc.z);
        acc.w = fmaf(v.w, w, acc.w);
    }
    *(float4*)&agg[(long)n * D + j] = acc;
}

// ---------------------------------------------------------------------------
// Fused GEMM (register-tiled, LDS-staged) — same as round 1
// ---------------------------------------------------------------------------
template<int KPER, bool NSPLIT, bool ACT>
__global__ __launch_bounds__(256)
void gemm_fused(const float* __restrict__ A0, const float* __restrict__ A1,
                const float* __restrict__ B0, const float* __restrict__ B1,
                const float* __restrict__ bias, float* __restrict__ C)
{
    __shared__ float lds_a[BM * SA];
    __shared__ float lds_b[BK * SB];

    const int tid = threadIdx.x;
    const int tm = tid >> 4;
    const int tn = tid & 15;
    const int m0 = blockIdx.x * BM;

    constexpr int NCH_PER = KPER / BK;
    constexpr int NCH = NSPLIT ? NCH_PER : 2 * NCH_PER;

    float acc[4][8] = {};
    const int boff = tn * 8 + (tn >> 2) * 4;

    for (int ch = 0; ch < NCH; ++ch) {
        const int k0 = (ch % NCH_PER) * BK;
        const bool first = NSPLIT || (ch < NCH_PER);
        const float* __restrict__ Asel = first ? A0 : A1;
        const float* __restrict__ Bsel = first ? B0 : B1;

        __syncthreads();
#pragma unroll
        for (int q = tid; q < BM * BK / 4; q += 256) {
            const int r  = q >> 3;
            const int kq = (q & 7) * 4;
            int row = m0 + r; if (row >= N_NODES) row = N_NODES - 1;
            const float4 v = *(const float4*)&Asel[(long)row * KPER + k0 + kq];
            *(float4*)&lds_a[r * SA + kq] = v;
        }
#pragma unroll
        for (int q = tid; q < 128 * BK / 4; q += 256) {
            const int c  = q >> 3;
            const int kq = (q & 7) * 4;
            const float* brow;
            if (NSPLIT) brow = (c < 64) ? (B0 + (long)c * KPER)
                                        : (B1 + (long)(c - 64) * KPER);
            else        brow = Bsel + (long)c * KPER;
            const float4 v = *(const float4*)&brow[k0 + kq];
            const int g = c >> 3;
            const int cp = g * 8 + (g >> 2) * 4 + (c & 7);
            lds_b[(kq + 0) * SB + cp] = v.x;
            lds_b[(kq + 1) * SB + cp] = v.y;
            lds_b[(kq + 2) * SB + cp] = v.z;
            lds_b[(kq + 3) * SB + cp] = v.w;
        }
        __syncthreads();

#pragma unroll 2
        for (int kk = 0; kk < BK; kk += 4) {
            float4 af[4];
#pragma unroll
            for (int i = 0; i < 4; ++i)
                af[i] = *(const float4*)&lds_a[(tm * 4 + i) * SA + kk];
#pragma unroll
            for (int j = 0; j < 4; ++j) {
                const float4 b0 = *(const float4*)&lds_b[(kk + j) * SB + boff];
                const float4 b1 = *(const float4*)&lds_b[(kk + j) * SB + boff + 4];
                const float bb[8] = {b0.x, b0.y, b0.z, b0.w, b1.x, b1.y, b1.z, b1.w};
#pragma unroll
                for (int i = 0; i < 4; ++i) {
                    const float a = (&af[i].x)[j];
#pragma unroll
                    for (int n = 0; n < 8; ++n)
                        acc[i][n] = fmaf(a, bb[n], acc[i][n]);
                }
            }
        }
    }

#pragma unroll
    for (int i = 0; i < 4; ++i) {
        const int m = m0 + tm * 4 + i;
        if (m >= N_NODES) break;
        float out[8];
#pragma unroll
        for (int n = 0; n < 8; ++n) {
            const int c = tn * 8 + n;
            const float b = NSPLIT ? (c < 64 ? 0.f : bias[c - 64]) : bias[c];
            const float v = acc[i][n] + b;
            out[n] = ACT ? tanhf(v) : v;
        }
        *(float4*)&C[(long)m * 128 + tn * 8]     = make_float4(out[0], out[1], out[2], out[3]);
        *(float4*)&C[(long)m * 128 + tn * 8 + 4] = make_float4(out[4], out[5], out[6], out[7]);
    }
}

// ---------------------------------------------------------------------------
// graph segment starts (batch is sorted): gstart[g] = first n with batch[n]>=g
// ---------------------------------------------------------------------------
__global__ void gstart_kernel(const int* __restrict__ batch, int* __restrict__ gstart)
{
    const int g = threadIdx.x;
    int lo = 0, hi = N_NODES;
    while (lo < hi) { const int mid = (lo + hi) >> 1; if (batch[mid] < g) lo = mid + 1; else hi = mid; }
    gstart[g] = lo;
    if (g == 0) gstart[N_GRAPHS] = N_NODES;
}

// ---------------------------------------------------------------------------
// pool: one block per graph; h3 = tanh(agg3 + root3); no atomics
// ---------------------------------------------------------------------------
__global__ __launch_bounds__(256)
void pool_seg_kernel(const float* __restrict__ agg3, const float* __restrict__ yr,
                     const int* __restrict__ gstart, float* __restrict__ g)
{
    const int gi = blockIdx.x;
    const int c = threadIdx.x & 63;
    const int sub = threadIdx.x >> 6;
    const int lo = gstart[gi], hi = gstart[gi + 1];
    float acc = 0.f;
    for (int n = lo + sub; n < hi; n += 4)
        acc += tanhf(agg3[(long)n * 64 + c] + yr[(long)n * 128 + 64 + c]);
    __shared__ float red[256];
    red[threadIdx.x] = acc;
    __syncthreads();
    if (sub == 0) g[gi * 64 + c] = red[c] + red[64 + c] + red[128 + c] + red[192 + c];
}

// ---------------------------------------------------------------------------
// MLP: one block (64 threads) per graph
// ---------------------------------------------------------------------------
__global__ __launch_bounds__(64)
void mlp_kernel(const float* __restrict__ g,
                const float* __restrict__ Wm1, const float* __restrict__ bm1,
                const float* __restrict__ Wm2, const float* __restrict__ bm2,
                const float* __restrict__ Wm3, const float* __restrict__ bm3,
                float* __restrict__ out)
{
    const int gi = blockIdx.x;
    const int l = threadIdx.x;
    __shared__ float gr[64], h1[32], h2[16];
    gr[l] = g[gi * 64 + l];
    __syncthreads();
    if (l < 32) {
        float a = bm1[l];
        const float* w = Wm1 + l * 64;
        for (int k = 0; k < 64; ++k) a = fmaf(gr[k], w[k], a);
        h1[l] = fmaxf(a, 0.f);
    }
    __syncthreads();
    if (l < 16) {
        float a = bm2[l];
        const float* w = Wm2 + l * 32;
        for (int k = 0; k < 32; ++k) a = fmaf(h1[k], w[k], a);
        h2[l] = fmaxf(a, 0.f);
    }
    __syncthreads();
    if (l == 0) {
        float a = bm3[0];
        for (int k = 0; k < 16; ++k) a = fmaf(h2[k], Wm3[k], a);
        out[gi] = a;
    }
}

extern "C" void kernel_launch(void* const* d_in, const int* in_sizes, int n_in,
                              void* d_out, int out_size, void* d_ws, size_t ws_size,
                              hipStream_t stream) {
    const float* x      = (const float*)d_in[0];
    const int*   ei     = (const int*)  d_in[1];
    const int*   batch  = (const int*)  d_in[2];
    const float* ew     = (const float*)d_in[3];
    const float* W1r    = (const float*)d_in[4];
    const float* b1     = (const float*)d_in[5];
    const float* W1root = (const float*)d_in[6];
    const float* W2r    = (const float*)d_in[7];
    const float* b2     = (const float*)d_in[8];
    const float* W2root = (const float*)d_in[9];
    const float* W3r    = (const float*)d_in[10];
    const float* b3     = (const float*)d_in[11];
    const float* W3root = (const float*)d_in[12];
    const float* Wm1    = (const float*)d_in[13];
    const float* bm1    = (const float*)d_in[14];
    const float* Wm2    = (const float*)d_in[15];
    const float* bm2    = (const float*)d_in[16];
    const float* Wm3    = (const float*)d_in[17];
    const float* bm3    = (const float*)d_in[18];
    float* out = (float*)d_out;

    // ---- workspace layout ----
    float* P0   = (float*)d_ws;                   // N*128 f
    float* P1   = P0 + (long)N_NODES * 128;       // N*128 f
    float* P2   = P1 + (long)N_NODES * 128;       // N*128 f
    float* POOL = P2 + (long)N_NODES * 128;       // 256*64 f
    int*   count   = (int*)(POOL + N_GRAPHS * 64);
    int*   offsets = count + N_NODES;             // N+1
    int*   cursor  = offsets + N_NODES + 1;       // N+1
    int*   esrc    = cursor + N_NODES + 1;        // E
    float* ewt     = (float*)(esrc + N_EDGES);    // E
    int*   gstart  = (int*)(ewt + N_EDGES);       // 257

    const int gemm_grid = (N_NODES + BM - 1) / BM;
    const int egrid = (N_EDGES + 255) / 256;

    // ---- CSR build (once, reused by all 3 layers) ----
    hipMemsetAsync(count, 0, N_NODES * sizeof(int), stream);
    count_kernel<<<egrid, 256, 0, stream>>>(ei, count);
    scan_kernel<<<1, 1024, 0, stream>>>(count, offsets, cursor);
    fill_kernel<<<egrid, 256, 0, stream>>>(ei, ew, cursor, esrc, ewt);
    gstart_kernel<<<1, 256, 0, stream>>>(batch, gstart);

    // ---- layer 1: agg1 (N x 64) in P2; h1 in P1 ----
    gather_agg<64><<<(N_NODES + 15) / 16, 256, 0, stream>>>(x, 64, offsets, esrc, ewt, P2);
    gemm_fused<64, false, true><<<gemm_grid, 256, 0, stream>>>(P2, x, W1r, W1root, b1, P1);

    // ---- layer 2: agg2 (N x 128) in P0; h2 in P2 ----
    gather_agg<128><<<(N_NODES + 7) / 8, 256, 0, stream>>>(P1, 128, offsets, esrc, ewt, P0);
    gemm_fused<128, false, true><<<gemm_grid, 256, 0, stream>>>(P0, P1, W2r, W2root, b2, P2);

    // ---- layer 3: yr (N x 128: [y3 | root3+b3]) in P1; agg3 (N x 64) in P0 ----
    gemm_fused<128, true, false><<<gemm_grid, 256, 0, stream>>>(P2, P2, W3r, W3root, b3, P1);
    gather_agg<64><<<(N_NODES + 15) / 16, 256, 0, stream>>>(P1, 128, offsets, esrc, ewt, P0);

    // ---- pool + MLP ----
    pool_seg_kernel<<<N_GRAPHS, 256, 0, stream>>>(P0, P1, gstart, POOL);
    mlp_kernel<<<N_GRAPHS, 64, 0, stream>>>(POOL, Wm1, bm1, Wm2, bm2, Wm3, bm3, out);
}

// Round 4
// 408.070 us; speedup vs baseline: 7.4778x; 1.2974x over previous
//
#include <hip/hip_runtime.h>

#define N_NODES 50000
#define N_EDGES 800000
#define N_GRAPHS 256

#define BM 64
#define BK 32
#define SA 36    // lds_a row stride (floats)
#define SB 144   // lds_b row stride (floats)

#define SCAN_B ((N_NODES + 255) / 256)   // 196 blocks

// ---------------------------------------------------------------------------
// CSR build: count -> hierarchical scan -> fill   (edges grouped by dst)
// ---------------------------------------------------------------------------
__global__ void count_kernel(const int* __restrict__ ei, int* __restrict__ count)
{
    const int e = blockIdx.x * blockDim.x + threadIdx.x;
    if (e < N_EDGES) atomicAdd(&count[ei[N_EDGES + e]], 1);
}

// stage 1: per-block sums of count[]
__global__ __launch_bounds__(256)
void scan_blocks_kernel(const int* __restrict__ count, int* __restrict__ blocksum)
{
    __shared__ int red[256];
    const int i = blockIdx.x * 256 + threadIdx.x;
    red[threadIdx.x] = (i < N_NODES) ? count[i] : 0;
    __syncthreads();
#pragma unroll
    for (int d = 128; d > 0; d >>= 1) {
        if (threadIdx.x < d) red[threadIdx.x] += red[threadIdx.x + d];
        __syncthreads();
    }
    if (threadIdx.x == 0) blocksum[blockIdx.x] = red[0];
}

// stage 2: exclusive scan of the block sums (one block)
__global__ __launch_bounds__(256)
void scan_base_kernel(const int* __restrict__ blocksum, int* __restrict__ blockbase)
{
    __shared__ int s[256];
    const int t = threadIdx.x;
    const int own = (t < SCAN_B) ? blocksum[t] : 0;
    s[t] = own;
    __syncthreads();
#pragma unroll
    for (int d = 1; d < 256; d <<= 1) {
        const int v = (t >= d) ? s[t - d] : 0;
        __syncthreads();
        s[t] += v;
        __syncthreads();
    }
    if (t < SCAN_B) blockbase[t] = s[t] - own;
}

// stage 3: local exclusive scan + base; writes offsets and cursor
__global__ __launch_bounds__(256)
void scan_final_kernel(const int* __restrict__ count, const int* __restrict__ blockbase,
                       int* __restrict__ offsets, int* __restrict__ cursor)
{
    __shared__ int s[256];
    const int t = threadIdx.x;
    const int i = blockIdx.x * 256 + t;
    const int v = (i < N_NODES) ? count[i] : 0;
    s[t] = v;
    __syncthreads();
#pragma unroll
    for (int d = 1; d < 256; d <<= 1) {
        const int u = (t >= d) ? s[t - d] : 0;
        __syncthreads();
        s[t] += u;
        __syncthreads();
    }
    if (i < N_NODES) {
        const int off = blockbase[blockIdx.x] + s[t] - v;
        offsets[i] = off;
        cursor[i] = off;
    }
    if (i == 0) offsets[N_NODES] = N_EDGES;
}

__global__ void fill_kernel(const int* __restrict__ ei, const float* __restrict__ ew,
                            int* __restrict__ cursor,
                            int* __restrict__ esrc, float* __restrict__ ewt)
{
    const int e = blockIdx.x * blockDim.x + threadIdx.x;
    if (e >= N_EDGES) return;
    const int t = ei[N_EDGES + e];
    const int pos = atomicAdd(&cursor[t], 1);
    esrc[pos] = ei[e];
    ewt[pos]  = ew[e];
}

// ---------------------------------------------------------------------------
// gather aggregation: agg[n][:] = sum_{e in csr[n]} ewt[e] * feat[esrc[e]][:]
// D/4 lanes per node, float4 per lane, register accumulate. No atomics.
// ---------------------------------------------------------------------------
template<int D>
__global__ __launch_bounds__(256)
void gather_agg(const float* __restrict__ feat, int stride,
                const int* __restrict__ offsets, const int* __restrict__ esrc,
                const float* __restrict__ ewt, float* __restrict__ agg)
{
    constexpr int LPN = D / 4;       // lanes per node
    constexpr int NPB = 256 / LPN;   // nodes per block
    const int lane = threadIdx.x % LPN;
    const int slot = threadIdx.x / LPN;
    const int n = blockIdx.x * NPB + slot;
    if (n >= N_NODES) return;
    const int lo = offsets[n], hi = offsets[n + 1];
    const int j = lane * 4;
    float4 acc = make_float4(0.f, 0.f, 0.f, 0.f);
#pragma unroll 2
    for (int e = lo; e < hi; ++e) {
        const int s = esrc[e];
        const float w = ewt[e];
        const float4 v = *(const float4*)&feat[(long)s * stride + j];
        acc.x = fmaf(v.x, w, acc.x);
        acc.y = fmaf(v.y, w, acc.y);
        acc.z = fmaf(v.z, w, acc.z);
        acc.w = fmaf(v.w, w, acc.w);
    }
    *(float4*)&agg[(long)n * D + j] = acc;
}

// ---------------------------------------------------------------------------
// Fused GEMM (register-tiled, LDS-staged)
// ---------------------------------------------------------------------------
template<int KPER, bool NSPLIT, bool ACT>
__global__ __launch_bounds__(256)
void gemm_fused(const float* __restrict__ A0, const float* __restrict__ A1,
                const float* __restrict__ B0, const float* __restrict__ B1,
                const float* __restrict__ bias, float* __restrict__ C)
{
    __shared__ float lds_a[BM * SA];
    __shared__ float lds_b[BK * SB];

    const int tid = threadIdx.x;
    const int tm = tid >> 4;
    const int tn = tid & 15;
    const int m0 = blockIdx.x * BM;

    constexpr int NCH_PER = KPER / BK;
    constexpr int NCH = NSPLIT ? NCH_PER : 2 * NCH_PER;

    float acc[4][8] = {};
    const int boff = tn * 8 + (tn >> 2) * 4;

    for (int ch = 0; ch < NCH; ++ch) {
        const int k0 = (ch % NCH_PER) * BK;
        const bool first = NSPLIT || (ch < NCH_PER);
        const float* __restrict__ Asel = first ? A0 : A1;
        const float* __restrict__ Bsel = first ? B0 : B1;

        __syncthreads();
#pragma unroll
        for (int q = tid; q < BM * BK / 4; q += 256) {
            const int r  = q >> 3;
            const int kq = (q & 7) * 4;
            int row = m0 + r; if (row >= N_NODES) row = N_NODES - 1;
            const float4 v = *(const float4*)&Asel[(long)row * KPER + k0 + kq];
            *(float4*)&lds_a[r * SA + kq] = v;
        }
#pragma unroll
        for (int q = tid; q < 128 * BK / 4; q += 256) {
            const int c  = q >> 3;
            const int kq = (q & 7) * 4;
            const float* brow;
            if (NSPLIT) brow = (c < 64) ? (B0 + (long)c * KPER)
                                        : (B1 + (long)(c - 64) * KPER);
            else        brow = Bsel + (long)c * KPER;
            const float4 v = *(const float4*)&brow[k0 + kq];
            const int g = c >> 3;
            const int cp = g * 8 + (g >> 2) * 4 + (c & 7);
            lds_b[(kq + 0) * SB + cp] = v.x;
            lds_b[(kq + 1) * SB + cp] = v.y;
            lds_b[(kq + 2) * SB + cp] = v.z;
            lds_b[(kq + 3) * SB + cp] = v.w;
        }
        __syncthreads();

#pragma unroll 2
        for (int kk = 0; kk < BK; kk += 4) {
            float4 af[4];
#pragma unroll
            for (int i = 0; i < 4; ++i)
                af[i] = *(const float4*)&lds_a[(tm * 4 + i) * SA + kk];
#pragma unroll
            for (int j = 0; j < 4; ++j) {
                const float4 b0 = *(const float4*)&lds_b[(kk + j) * SB + boff];
                const float4 b1 = *(const float4*)&lds_b[(kk + j) * SB + boff + 4];
                const float bb[8] = {b0.x, b0.y, b0.z, b0.w, b1.x, b1.y, b1.z, b1.w};
#pragma unroll
                for (int i = 0; i < 4; ++i) {
                    const float a = (&af[i].x)[j];
#pragma unroll
                    for (int n = 0; n < 8; ++n)
                        acc[i][n] = fmaf(a, bb[n], acc[i][n]);
                }
            }
        }
    }

#pragma unroll
    for (int i = 0; i < 4; ++i) {
        const int m = m0 + tm * 4 + i;
        if (m >= N_NODES) break;
        float out[8];
#pragma unroll
        for (int n = 0; n < 8; ++n) {
            const int c = tn * 8 + n;
            const float b = NSPLIT ? (c < 64 ? 0.f : bias[c - 64]) : bias[c];
            const float v = acc[i][n] + b;
            out[n] = ACT ? tanhf(v) : v;
        }
        *(float4*)&C[(long)m * 128 + tn * 8]     = make_float4(out[0], out[1], out[2], out[3]);
        *(float4*)&C[(long)m * 128 + tn * 8 + 4] = make_float4(out[4], out[5], out[6], out[7]);
    }
}

// ---------------------------------------------------------------------------
// graph segment starts (batch is sorted)
// ---------------------------------------------------------------------------
__global__ void gstart_kernel(const int* __restrict__ batch, int* __restrict__ gstart)
{
    const int g = threadIdx.x;
    int lo = 0, hi = N_NODES;
    while (lo < hi) { const int mid = (lo + hi) >> 1; if (batch[mid] < g) lo = mid + 1; else hi = mid; }
    gstart[g] = lo;
    if (g == 0) gstart[N_GRAPHS] = N_NODES;
}

// ---------------------------------------------------------------------------
// pool: one block per graph; h3 = tanh(agg3 + root3); no atomics
// ---------------------------------------------------------------------------
__global__ __launch_bounds__(256)
void pool_seg_kernel(const float* __restrict__ agg3, const float* __restrict__ yr,
                     const int* __restrict__ gstart, float* __restrict__ g)
{
    const int gi = blockIdx.x;
    const int c = threadIdx.x & 63;
    const int sub = threadIdx.x >> 6;
    const int lo = gstart[gi], hi = gstart[gi + 1];
    float acc = 0.f;
    for (int n = lo + sub; n < hi; n += 4)
        acc += tanhf(agg3[(long)n * 64 + c] + yr[(long)n * 128 + 64 + c]);
    __shared__ float red[256];
    red[threadIdx.x] = acc;
    __syncthreads();
    if (sub == 0) g[gi * 64 + c] = red[c] + red[64 + c] + red[128 + c] + red[192 + c];
}

// ---------------------------------------------------------------------------
// MLP: one block (64 threads) per graph
// ---------------------------------------------------------------------------
__global__ __launch_bounds__(64)
void mlp_kernel(const float* __restrict__ g,
                const float* __restrict__ Wm1, const float* __restrict__ bm1,
                const float* __restrict__ Wm2, const float* __restrict__ bm2,
                const float* __restrict__ Wm3, const float* __restrict__ bm3,
                float* __restrict__ out)
{
    const int gi = blockIdx.x;
    const int l = threadIdx.x;
    __shared__ float gr[64], h1[32], h2[16];
    gr[l] = g[gi * 64 + l];
    __syncthreads();
    if (l < 32) {
        float a = bm1[l];
        const float* w = Wm1 + l * 64;
        for (int k = 0; k < 64; ++k) a = fmaf(gr[k], w[k], a);
        h1[l] = fmaxf(a, 0.f);
    }
    __syncthreads();
    if (l < 16) {
        float a = bm2[l];
        const float* w = Wm2 + l * 32;
        for (int k = 0; k < 32; ++k) a = fmaf(h1[k], w[k], a);
        h2[l] = fmaxf(a, 0.f);
    }
    __syncthreads();
    if (l == 0) {
        float a = bm3[0];
        for (int k = 0; k < 16; ++k) a = fmaf(h2[k], Wm3[k], a);
        out[gi] = a;
    }
}

extern "C" void kernel_launch(void* const* d_in, const int* in_sizes, int n_in,
                              void* d_out, int out_size, void* d_ws, size_t ws_size,
                              hipStream_t stream) {
    const float* x      = (const float*)d_in[0];
    const int*   ei     = (const int*)  d_in[1];
    const int*   batch  = (const int*)  d_in[2];
    const float* ew     = (const float*)d_in[3];
    const float* W1r    = (const float*)d_in[4];
    const float* b1     = (const float*)d_in[5];
    const float* W1root = (const float*)d_in[6];
    const float* W2r    = (const float*)d_in[7];
    const float* b2     = (const float*)d_in[8];
    const float* W2root = (const float*)d_in[9];
    const float* W3r    = (const float*)d_in[10];
    const float* b3     = (const float*)d_in[11];
    const float* W3root = (const float*)d_in[12];
    const float* Wm1    = (const float*)d_in[13];
    const float* bm1    = (const float*)d_in[14];
    const float* Wm2    = (const float*)d_in[15];
    const float* bm2    = (const float*)d_in[16];
    const float* Wm3    = (const float*)d_in[17];
    const float* bm3    = (const float*)d_in[18];
    float* out = (float*)d_out;

    // ---- workspace layout ----
    float* P0   = (float*)d_ws;                   // N*128 f
    float* P1   = P0 + (long)N_NODES * 128;       // N*128 f
    float* P2   = P1 + (long)N_NODES * 128;       // N*128 f
    float* POOL = P2 + (long)N_NODES * 128;       // 256*64 f
    int*   count    = (int*)(POOL + N_GRAPHS * 64);
    int*   offsets  = count + N_NODES;            // N+1
    int*   cursor   = offsets + N_NODES + 1;      // N+1
    int*   esrc     = cursor + N_NODES + 1;       // E
    float* ewt      = (float*)(esrc + N_EDGES);   // E
    int*   gstart   = (int*)(ewt + N_EDGES);      // 257
    int*   blocksum = gstart + N_GRAPHS + 1;      // SCAN_B
    int*   blockbase= blocksum + SCAN_B;          // SCAN_B

    const int gemm_grid = (N_NODES + BM - 1) / BM;
    const int egrid = (N_EDGES + 255) / 256;

    // ---- CSR build (once, reused by all 3 layers) ----
    hipMemsetAsync(count, 0, N_NODES * sizeof(int), stream);
    count_kernel<<<egrid, 256, 0, stream>>>(ei, count);
    scan_blocks_kernel<<<SCAN_B, 256, 0, stream>>>(count, blocksum);
    scan_base_kernel<<<1, 256, 0, stream>>>(blocksum, blockbase);
    scan_final_kernel<<<SCAN_B, 256, 0, stream>>>(count, blockbase, offsets, cursor);
    fill_kernel<<<egrid, 256, 0, stream>>>(ei, ew, cursor, esrc, ewt);
    gstart_kernel<<<1, 256, 0, stream>>>(batch, gstart);

    // ---- layer 1: agg1 (N x 64) in P2; h1 in P1 ----
    gather_agg<64><<<(N_NODES + 15) / 16, 256, 0, stream>>>(x, 64, offsets, esrc, ewt, P2);
    gemm_fused<64, false, true><<<gemm_grid, 256, 0, stream>>>(P2, x, W1r, W1root, b1, P1);

    // ---- layer 2: agg2 (N x 128) in P0; h2 in P2 ----
    gather_agg<128><<<(N_NODES + 7) / 8, 256, 0, stream>>>(P1, 128, offsets, esrc, ewt, P0);
    gemm_fused<128, false, true><<<gemm_grid, 256, 0, stream>>>(P0, P1, W2r, W2root, b2, P2);

    // ---- layer 3: yr (N x 128: [y3 | root3+b3]) in P1; agg3 (N x 64) in P0 ----
    gemm_fused<128, true, false><<<gemm_grid, 256, 0, stream>>>(P2, P2, W3r, W3root, b3, P1);
    gather_agg<64><<<(N_NODES + 15) / 16, 256, 0, stream>>>(P1, 128, offsets, esrc, ewt, P0);

    // ---- pool + MLP ----
    pool_seg_kernel<<<N_GRAPHS, 256, 0, stream>>>(P0, P1, gstart, POOL);
    mlp_kernel<<<N_GRAPHS, 64, 0, stream>>>(POOL, Wm1, bm1, Wm2, bm2, Wm3, bm3, out);
}

// Round 5
// 319.006 us; speedup vs baseline: 9.5655x; 1.2792x over previous
//
#include <hip/hip_runtime.h>

#define N_NODES 50000
#define N_EDGES 800000
#define N_GRAPHS 256
#define SCAN_B ((N_NODES + 255) / 256)

typedef __attribute__((ext_vector_type(8))) short bf16x8;
typedef __attribute__((ext_vector_type(4))) float f32x4;

__device__ inline unsigned short f2bf(float f) {
    unsigned int u = __float_as_uint(f);
    u += 0x7fff + ((u >> 16) & 1);          // RNE
    return (unsigned short)(u >> 16);
}
__device__ inline float bf2f(unsigned short h) {
    return __uint_as_float(((unsigned int)h) << 16);
}
__device__ inline float fast_tanh(float x) {
    return 1.0f - 2.0f / (__expf(2.0f * x) + 1.0f);
}

// ---------------------------------------------------------------------------
// weight pre-split: fp32 -> packed bf16 hi/lo, concatenated [128][KTOT]
// kconcat (nconcat=0): row c = [s0[c][0:K0] | s1[c][0:K0]]
// nconcat (nconcat=1): row c = (c<64 ? s0[c] : s1[c-64])[0:KTOT]
// ---------------------------------------------------------------------------
__global__ void pack_w_kernel(const float* __restrict__ s0, const float* __restrict__ s1,
                              int K0, int KTOT, int nconcat,
                              unsigned short* __restrict__ hi, unsigned short* __restrict__ lo)
{
    const int idx = blockIdx.x * 256 + threadIdx.x;
    if (idx >= 128 * KTOT) return;
    const int c = idx / KTOT, k = idx % KTOT;
    float v;
    if (nconcat) v = (c < 64) ? s0[c * KTOT + k] : s1[(c - 64) * KTOT + k];
    else         v = (k < K0) ? s0[c * K0 + k]   : s1[c * K0 + (k - K0)];
    const unsigned short h = f2bf(v);
    hi[idx] = h;
    lo[idx] = f2bf(v - bf2f(h));
}

// ---------------------------------------------------------------------------
// MFMA GEMM: C[m][0:128] = act( [A0|A1][m][0:KTOT] @ Bcat^T + bias )
// bf16x3 split product: ah*bh + al*bh + ah*bl, fp32 accumulate.
// Block: 256 thr (4 waves), BM=64. Wave w owns cols [w*32, w*32+32).
// ---------------------------------------------------------------------------
template<int KTOT, bool KSPLIT, bool NBIAS, bool ACT>
__global__ __launch_bounds__(256)
void gemm_mfma(const float* __restrict__ A0, const float* __restrict__ A1, int astr,
               const unsigned short* __restrict__ Bhi, const unsigned short* __restrict__ Blo,
               const float* __restrict__ bias, float* __restrict__ C)
{
    __shared__ __align__(16) unsigned short lah[64 * 40];
    __shared__ __align__(16) unsigned short lal[64 * 40];
    __shared__ __align__(16) unsigned short lbh[128 * 40];
    __shared__ __align__(16) unsigned short lbl[128 * 40];

    const int tid = threadIdx.x;
    const int w = tid >> 6;
    const int lane = tid & 63;
    const int lrow = lane & 15;
    const int lkb = lane >> 4;
    const int m0 = blockIdx.x * 64;

    constexpr int NCH = KTOT / 32;
    f32x4 acc[4][2] = {};

    for (int ch = 0; ch < NCH; ++ch) {
        const float* __restrict__ Asel;
        int ak0;
        if (KSPLIT) {
            Asel = (ch < NCH / 2) ? A0 : A1;
            ak0 = (ch % (NCH / 2)) * 32;
        } else { Asel = A0; ak0 = ch * 32; }
        const int bk0 = ch * 32;

        __syncthreads();
        // ---- stage A: 64x32 fp32 -> hi/lo bf16 (lds stride 40 shorts) ----
#pragma unroll
        for (int p = 0; p < 2; ++p) {
            const int f = tid + p * 256;   // 0..511
            const int r = f >> 3;          // row 0..63
            const int q = f & 7;           // float4 within row
            int row = m0 + r; if (row >= N_NODES) row = N_NODES - 1;
            const float4 v = *(const float4*)&Asel[(long)row * astr + ak0 + q * 4];
            const unsigned short h0 = f2bf(v.x), h1 = f2bf(v.y), h2 = f2bf(v.z), h3 = f2bf(v.w);
            *(ushort4*)&lah[r * 40 + q * 4] = make_ushort4(h0, h1, h2, h3);
            *(ushort4*)&lal[r * 40 + q * 4] =
                make_ushort4(f2bf(v.x - bf2f(h0)), f2bf(v.y - bf2f(h1)),
                             f2bf(v.z - bf2f(h2)), f2bf(v.w - bf2f(h3)));
        }
        // ---- stage B: copy pre-split bf16 128x32 (hi & lo) ----
#pragma unroll
        for (int p = 0; p < 2; ++p) {
            const int f = tid + p * 256;   // 0..511
            const int r = f >> 2;          // row 0..127
            const int q = f & 3;           // short8 within row
            const long g = (long)r * KTOT + bk0 + q * 8;
            *(uint4*)&lbh[r * 40 + q * 8] = *(const uint4*)&Bhi[g];
            *(uint4*)&lbl[r * 40 + q * 8] = *(const uint4*)&Blo[g];
        }
        __syncthreads();

        const int bo0 = (w * 32 + lrow) * 40 + lkb * 8;
        const int bo1 = bo0 + 16 * 40;
        const bf16x8 bh0 = *(const bf16x8*)&lbh[bo0];
        const bf16x8 bh1 = *(const bf16x8*)&lbh[bo1];
        const bf16x8 bl0 = *(const bf16x8*)&lbl[bo0];
        const bf16x8 bl1 = *(const bf16x8*)&lbl[bo1];
#pragma unroll
        for (int m = 0; m < 4; ++m) {
            const int ao = (m * 16 + lrow) * 40 + lkb * 8;
            const bf16x8 ah = *(const bf16x8*)&lah[ao];
            const bf16x8 al = *(const bf16x8*)&lal[ao];
            acc[m][0] = __builtin_amdgcn_mfma_f32_16x16x32_bf16(ah, bh0, acc[m][0], 0, 0, 0);
            acc[m][1] = __builtin_amdgcn_mfma_f32_16x16x32_bf16(ah, bh1, acc[m][1], 0, 0, 0);
            acc[m][0] = __builtin_amdgcn_mfma_f32_16x16x32_bf16(al, bh0, acc[m][0], 0, 0, 0);
            acc[m][1] = __builtin_amdgcn_mfma_f32_16x16x32_bf16(al, bh1, acc[m][1], 0, 0, 0);
            acc[m][0] = __builtin_amdgcn_mfma_f32_16x16x32_bf16(ah, bl0, acc[m][0], 0, 0, 0);
            acc[m][1] = __builtin_amdgcn_mfma_f32_16x16x32_bf16(ah, bl1, acc[m][1], 0, 0, 0);
        }
    }

    // ---- epilogue ----
    const int c0 = w * 32 + lrow;
    float bb0, bb1;
    if (NBIAS) {
        bb0 = (c0 < 64) ? 0.f : bias[c0 - 64];
        bb1 = (c0 + 16 < 64) ? 0.f : bias[c0 + 16 - 64];
    } else { bb0 = bias[c0]; bb1 = bias[c0 + 16]; }
#pragma unroll
    for (int m = 0; m < 4; ++m) {
#pragma unroll
        for (int r = 0; r < 4; ++r) {
            const int row = m0 + m * 16 + lkb * 4 + r;
            if (row < N_NODES) {
                const float v0 = acc[m][0][r] + bb0;
                const float v1 = acc[m][1][r] + bb1;
                C[(long)row * 128 + c0]      = ACT ? fast_tanh(v0) : v0;
                C[(long)row * 128 + c0 + 16] = ACT ? fast_tanh(v1) : v1;
            }
        }
    }
}

// ---------------------------------------------------------------------------
// CSR build: count -> hierarchical scan -> fill
// ---------------------------------------------------------------------------
__global__ void count_kernel(const int* __restrict__ ei, int* __restrict__ count)
{
    const int e = blockIdx.x * blockDim.x + threadIdx.x;
    if (e < N_EDGES) atomicAdd(&count[ei[N_EDGES + e]], 1);
}

__global__ __launch_bounds__(256)
void scan_blocks_kernel(const int* __restrict__ count, int* __restrict__ blocksum)
{
    __shared__ int red[256];
    const int i = blockIdx.x * 256 + threadIdx.x;
    red[threadIdx.x] = (i < N_NODES) ? count[i] : 0;
    __syncthreads();
#pragma unroll
    for (int d = 128; d > 0; d >>= 1) {
        if (threadIdx.x < d) red[threadIdx.x] += red[threadIdx.x + d];
        __syncthreads();
    }
    if (threadIdx.x == 0) blocksum[blockIdx.x] = red[0];
}

__global__ __launch_bounds__(256)
void scan_base_kernel(const int* __restrict__ blocksum, int* __restrict__ blockbase)
{
    __shared__ int s[256];
    const int t = threadIdx.x;
    const int own = (t < SCAN_B) ? blocksum[t] : 0;
    s[t] = own;
    __syncthreads();
#pragma unroll
    for (int d = 1; d < 256; d <<= 1) {
        const int v = (t >= d) ? s[t - d] : 0;
        __syncthreads();
        s[t] += v;
        __syncthreads();
    }
    if (t < SCAN_B) blockbase[t] = s[t] - own;
}

__global__ __launch_bounds__(256)
void scan_final_kernel(const int* __restrict__ count, const int* __restrict__ blockbase,
                       int* __restrict__ offsets, int* __restrict__ cursor)
{
    __shared__ int s[256];
    const int t = threadIdx.x;
    const int i = blockIdx.x * 256 + t;
    const int v = (i < N_NODES) ? count[i] : 0;
    s[t] = v;
    __syncthreads();
#pragma unroll
    for (int d = 1; d < 256; d <<= 1) {
        const int u = (t >= d) ? s[t - d] : 0;
        __syncthreads();
        s[t] += u;
        __syncthreads();
    }
    if (i < N_NODES) {
        const int off = blockbase[blockIdx.x] + s[t] - v;
        offsets[i] = off;
        cursor[i] = off;
    }
    if (i == 0) offsets[N_NODES] = N_EDGES;
}

__global__ void fill_kernel(const int* __restrict__ ei, const float* __restrict__ ew,
                            int* __restrict__ cursor,
                            int* __restrict__ esrc, float* __restrict__ ewt)
{
    const int e = blockIdx.x * blockDim.x + threadIdx.x;
    if (e >= N_EDGES) return;
    const int t = ei[N_EDGES + e];
    const int pos = atomicAdd(&cursor[t], 1);
    esrc[pos] = ei[e];
    ewt[pos]  = ew[e];
}

// ---------------------------------------------------------------------------
// gather aggregation (CSR): no atomics
// ---------------------------------------------------------------------------
template<int D>
__global__ __launch_bounds__(256)
void gather_agg(const float* __restrict__ feat, int stride,
                const int* __restrict__ offsets, const int* __restrict__ esrc,
                const float* __restrict__ ewt, float* __restrict__ agg)
{
    constexpr int LPN = D / 4;
    constexpr int NPB = 256 / LPN;
    const int lane = threadIdx.x % LPN;
    const int slot = threadIdx.x / LPN;
    const int n = blockIdx.x * NPB + slot;
    if (n >= N_NODES) return;
    const int lo = offsets[n], hi = offsets[n + 1];
    const int j = lane * 4;
    float4 acc = make_float4(0.f, 0.f, 0.f, 0.f);
#pragma unroll 2
    for (int e = lo; e < hi; ++e) {
        const int s = esrc[e];
        const float w = ewt[e];
        const float4 v = *(const float4*)&feat[(long)s * stride + j];
        acc.x = fmaf(v.x, w, acc.x);
        acc.y = fmaf(v.y, w, acc.y);
        acc.z = fmaf(v.z, w, acc.z);
        acc.w = fmaf(v.w, w, acc.w);
    }
    *(float4*)&agg[(long)n * D + j] = acc;
}

// ---------------------------------------------------------------------------
// pool + MLP
// ---------------------------------------------------------------------------
__global__ void gstart_kernel(const int* __restrict__ batch, int* __restrict__ gstart)
{
    const int g = threadIdx.x;
    int lo = 0, hi = N_NODES;
    while (lo < hi) { const int mid = (lo + hi) >> 1; if (batch[mid] < g) lo = mid + 1; else hi = mid; }
    gstart[g] = lo;
    if (g == 0) gstart[N_GRAPHS] = N_NODES;
}

__global__ __launch_bounds__(256)
void pool_seg_kernel(const float* __restrict__ agg3, const float* __restrict__ yr,
                     const int* __restrict__ gstart, float* __restrict__ g)
{
    const int gi = blockIdx.x;
    const int c = threadIdx.x & 63;
    const int sub = threadIdx.x >> 6;
    const int lo = gstart[gi], hi = gstart[gi + 1];
    float acc = 0.f;
    for (int n = lo + sub; n < hi; n += 4)
        acc += fast_tanh(agg3[(long)n * 64 + c] + yr[(long)n * 128 + 64 + c]);
    __shared__ float red[256];
    red[threadIdx.x] = acc;
    __syncthreads();
    if (sub == 0) g[gi * 64 + c] = red[c] + red[64 + c] + red[128 + c] + red[192 + c];
}

__global__ __launch_bounds__(64)
void mlp_kernel(const float* __restrict__ g,
                const float* __restrict__ Wm1, const float* __restrict__ bm1,
                const float* __restrict__ Wm2, const float* __restrict__ bm2,
                const float* __restrict__ Wm3, const float* __restrict__ bm3,
                float* __restrict__ out)
{
    const int gi = blockIdx.x;
    const int l = threadIdx.x;
    __shared__ float gr[64], h1[32], h2[16];
    gr[l] = g[gi * 64 + l];
    __syncthreads();
    if (l < 32) {
        float a = bm1[l];
        const float* w = Wm1 + l * 64;
        for (int k = 0; k < 64; ++k) a = fmaf(gr[k], w[k], a);
        h1[l] = fmaxf(a, 0.f);
    }
    __syncthreads();
    if (l < 16) {
        float a = bm2[l];
        const float* w = Wm2 + l * 32;
        for (int k = 0; k < 32; ++k) a = fmaf(h1[k], w[k], a);
        h2[l] = fmaxf(a, 0.f);
    }
    __syncthreads();
    if (l == 0) {
        float a = bm3[0];
        for (int k = 0; k < 16; ++k) a = fmaf(h2[k], Wm3[k], a);
        out[gi] = a;
    }
}

extern "C" void kernel_launch(void* const* d_in, const int* in_sizes, int n_in,
                              void* d_out, int out_size, void* d_ws, size_t ws_size,
                              hipStream_t stream) {
    const float* x      = (const float*)d_in[0];
    const int*   ei     = (const int*)  d_in[1];
    const int*   batch  = (const int*)  d_in[2];
    const float* ew     = (const float*)d_in[3];
    const float* W1r    = (const float*)d_in[4];
    const float* b1     = (const float*)d_in[5];
    const float* W1root = (const float*)d_in[6];
    const float* W2r    = (const float*)d_in[7];
    const float* b2     = (const float*)d_in[8];
    const float* W2root = (const float*)d_in[9];
    const float* W3r    = (const float*)d_in[10];
    const float* b3     = (const float*)d_in[11];
    const float* W3root = (const float*)d_in[12];
    const float* Wm1    = (const float*)d_in[13];
    const float* bm1    = (const float*)d_in[14];
    const float* Wm2    = (const float*)d_in[15];
    const float* bm2    = (const float*)d_in[16];
    const float* Wm3    = (const float*)d_in[17];
    const float* bm3    = (const float*)d_in[18];
    float* out = (float*)d_out;

    // ---- workspace layout ----
    float* P0   = (float*)d_ws;                   // N*128 f
    float* P1   = P0 + (long)N_NODES * 128;
    float* P2   = P1 + (long)N_NODES * 128;
    float* POOL = P2 + (long)N_NODES * 128;       // 256*64 f
    int*   count    = (int*)(POOL + N_GRAPHS * 64);
    int*   offsets  = count + N_NODES;            // N+1
    int*   cursor   = offsets + N_NODES + 1;      // N+1
    int*   esrc     = cursor + N_NODES + 1;       // E
    float* ewt      = (float*)(esrc + N_EDGES);   // E
    int*   gstart   = (int*)(ewt + N_EDGES);      // 257
    int*   blocksum = gstart + N_GRAPHS + 1;      // SCAN_B
    int*   blockbase= blocksum + SCAN_B;          // SCAN_B
    uintptr_t wp = ((uintptr_t)(blockbase + SCAN_B) + 15) & ~(uintptr_t)15;
    unsigned short* Bh1 = (unsigned short*)wp;    // 128*128
    unsigned short* Bl1 = Bh1 + 128 * 128;
    unsigned short* Bh2 = Bl1 + 128 * 128;        // 128*256
    unsigned short* Bl2 = Bh2 + 128 * 256;
    unsigned short* Bh3 = Bl2 + 128 * 256;        // 128*128
    unsigned short* Bl3 = Bh3 + 128 * 128;

    const int gemm_grid = (N_NODES + 63) / 64;    // 782
    const int egrid = (N_EDGES + 255) / 256;

    // ---- weight pre-split (bf16 hi/lo) ----
    pack_w_kernel<<<(128 * 128 + 255) / 256, 256, 0, stream>>>(W1r, W1root, 64, 128, 0, Bh1, Bl1);
    pack_w_kernel<<<(128 * 256 + 255) / 256, 256, 0, stream>>>(W2r, W2root, 128, 256, 0, Bh2, Bl2);
    pack_w_kernel<<<(128 * 128 + 255) / 256, 256, 0, stream>>>(W3r, W3root, 128, 128, 1, Bh3, Bl3);

    // ---- CSR build ----
    hipMemsetAsync(count, 0, N_NODES * sizeof(int), stream);
    count_kernel<<<egrid, 256, 0, stream>>>(ei, count);
    scan_blocks_kernel<<<SCAN_B, 256, 0, stream>>>(count, blocksum);
    scan_base_kernel<<<1, 256, 0, stream>>>(blocksum, blockbase);
    scan_final_kernel<<<SCAN_B, 256, 0, stream>>>(count, blockbase, offsets, cursor);
    fill_kernel<<<egrid, 256, 0, stream>>>(ei, ew, cursor, esrc, ewt);
    gstart_kernel<<<1, 256, 0, stream>>>(batch, gstart);

    // ---- layer 1: agg1 (N x 64) in P2; h1 in P1 ----
    gather_agg<64><<<(N_NODES + 15) / 16, 256, 0, stream>>>(x, 64, offsets, esrc, ewt, P2);
    gemm_mfma<128, true, false, true><<<gemm_grid, 256, 0, stream>>>(P2, x, 64, Bh1, Bl1, b1, P1);

    // ---- layer 2: agg2 (N x 128) in P0; h2 in P2 ----
    gather_agg<128><<<(N_NODES + 7) / 8, 256, 0, stream>>>(P1, 128, offsets, esrc, ewt, P0);
    gemm_mfma<256, true, false, true><<<gemm_grid, 256, 0, stream>>>(P0, P1, 128, Bh2, Bl2, b2, P2);

    // ---- layer 3: yr (N x 128: [y3 | root3+b3]) in P1; agg3 (N x 64) in P0 ----
    gemm_mfma<128, false, true, false><<<gemm_grid, 256, 0, stream>>>(P2, P2, 128, Bh3, Bl3, b3, P1);
    gather_agg<64><<<(N_NODES + 15) / 16, 256, 0, stream>>>(P1, 128, offsets, esrc, ewt, P0);

    // ---- pool + MLP ----
    pool_seg_kernel<<<N_GRAPHS, 256, 0, stream>>>(P0, P1, gstart, POOL);
    mlp_kernel<<<N_GRAPHS, 64, 0, stream>>>(POOL, Wm1, bm1, Wm2, bm2, Wm3, bm3, out);
}

// Round 6
// 302.156 us; speedup vs baseline: 10.0989x; 1.0558x over previous
//
#include <hip/hip_runtime.h>

#define N_NODES 50000
#define N_EDGES 800000
#define N_GRAPHS 256
#define SCAN_B ((N_NODES + 255) / 256)
#define FILL_GROUPS 8
#define NPG (N_NODES / FILL_GROUPS)   // 6250 nodes per group

typedef __attribute__((ext_vector_type(8))) short bf16x8;
typedef __attribute__((ext_vector_type(4))) float f32x4;

__device__ inline unsigned short f2bf(float f) {
    unsigned int u = __float_as_uint(f);
    u += 0x7fff + ((u >> 16) & 1);          // RNE
    return (unsigned short)(u >> 16);
}
__device__ inline float bf2f(unsigned short h) {
    return __uint_as_float(((unsigned int)h) << 16);
}
__device__ inline float fast_tanh(float x) {
    return 1.0f - 2.0f / (__expf(2.0f * x) + 1.0f);
}

// ---------------------------------------------------------------------------
// weight pre-split: fp32 -> packed bf16 hi/lo, concatenated [128][KTOT]
// ---------------------------------------------------------------------------
__global__ void pack_w_kernel(const float* __restrict__ s0, const float* __restrict__ s1,
                              int K0, int KTOT, int nconcat,
                              unsigned short* __restrict__ hi, unsigned short* __restrict__ lo)
{
    const int idx = blockIdx.x * 256 + threadIdx.x;
    if (idx >= 128 * KTOT) return;
    const int c = idx / KTOT, k = idx % KTOT;
    float v;
    if (nconcat) v = (c < 64) ? s0[c * KTOT + k] : s1[(c - 64) * KTOT + k];
    else         v = (k < K0) ? s0[c * K0 + k]   : s1[c * K0 + (k - K0)];
    const unsigned short h = f2bf(v);
    hi[idx] = h;
    lo[idx] = f2bf(v - bf2f(h));
}

// ---------------------------------------------------------------------------
// MFMA GEMM: C[m][0:128] = act( [A0|A1][m][0:KTOT] @ Bcat^T + bias )
// bf16x3 split product: ah*bh + al*bh + ah*bl, fp32 accumulate.
// ---------------------------------------------------------------------------
template<int KTOT, bool KSPLIT, bool NBIAS, bool ACT>
__global__ __launch_bounds__(256)
void gemm_mfma(const float* __restrict__ A0, const float* __restrict__ A1, int astr,
               const unsigned short* __restrict__ Bhi, const unsigned short* __restrict__ Blo,
               const float* __restrict__ bias, float* __restrict__ C)
{
    __shared__ __align__(16) unsigned short lah[64 * 40];
    __shared__ __align__(16) unsigned short lal[64 * 40];
    __shared__ __align__(16) unsigned short lbh[128 * 40];
    __shared__ __align__(16) unsigned short lbl[128 * 40];

    const int tid = threadIdx.x;
    const int w = tid >> 6;
    const int lane = tid & 63;
    const int lrow = lane & 15;
    const int lkb = lane >> 4;
    const int m0 = blockIdx.x * 64;

    constexpr int NCH = KTOT / 32;
    f32x4 acc[4][2] = {};

    for (int ch = 0; ch < NCH; ++ch) {
        const float* __restrict__ Asel;
        int ak0;
        if (KSPLIT) {
            Asel = (ch < NCH / 2) ? A0 : A1;
            ak0 = (ch % (NCH / 2)) * 32;
        } else { Asel = A0; ak0 = ch * 32; }
        const int bk0 = ch * 32;

        __syncthreads();
#pragma unroll
        for (int p = 0; p < 2; ++p) {
            const int f = tid + p * 256;
            const int r = f >> 3;
            const int q = f & 7;
            int row = m0 + r; if (row >= N_NODES) row = N_NODES - 1;
            const float4 v = *(const float4*)&Asel[(long)row * astr + ak0 + q * 4];
            const unsigned short h0 = f2bf(v.x), h1 = f2bf(v.y), h2 = f2bf(v.z), h3 = f2bf(v.w);
            *(ushort4*)&lah[r * 40 + q * 4] = make_ushort4(h0, h1, h2, h3);
            *(ushort4*)&lal[r * 40 + q * 4] =
                make_ushort4(f2bf(v.x - bf2f(h0)), f2bf(v.y - bf2f(h1)),
                             f2bf(v.z - bf2f(h2)), f2bf(v.w - bf2f(h3)));
        }
#pragma unroll
        for (int p = 0; p < 2; ++p) {
            const int f = tid + p * 256;
            const int r = f >> 2;
            const int q = f & 3;
            const long g = (long)r * KTOT + bk0 + q * 8;
            *(uint4*)&lbh[r * 40 + q * 8] = *(const uint4*)&Bhi[g];
            *(uint4*)&lbl[r * 40 + q * 8] = *(const uint4*)&Blo[g];
        }
        __syncthreads();

        const int bo0 = (w * 32 + lrow) * 40 + lkb * 8;
        const int bo1 = bo0 + 16 * 40;
        const bf16x8 bh0 = *(const bf16x8*)&lbh[bo0];
        const bf16x8 bh1 = *(const bf16x8*)&lbh[bo1];
        const bf16x8 bl0 = *(const bf16x8*)&lbl[bo0];
        const bf16x8 bl1 = *(const bf16x8*)&lbl[bo1];
#pragma unroll
        for (int m = 0; m < 4; ++m) {
            const int ao = (m * 16 + lrow) * 40 + lkb * 8;
            const bf16x8 ah = *(const bf16x8*)&lah[ao];
            const bf16x8 al = *(const bf16x8*)&lal[ao];
            acc[m][0] = __builtin_amdgcn_mfma_f32_16x16x32_bf16(ah, bh0, acc[m][0], 0, 0, 0);
            acc[m][1] = __builtin_amdgcn_mfma_f32_16x16x32_bf16(ah, bh1, acc[m][1], 0, 0, 0);
            acc[m][0] = __builtin_amdgcn_mfma_f32_16x16x32_bf16(al, bh0, acc[m][0], 0, 0, 0);
            acc[m][1] = __builtin_amdgcn_mfma_f32_16x16x32_bf16(al, bh1, acc[m][1], 0, 0, 0);
            acc[m][0] = __builtin_amdgcn_mfma_f32_16x16x32_bf16(ah, bl0, acc[m][0], 0, 0, 0);
            acc[m][1] = __builtin_amdgcn_mfma_f32_16x16x32_bf16(ah, bl1, acc[m][1], 0, 0, 0);
        }
    }

    const int c0 = w * 32 + lrow;
    float bb0, bb1;
    if (NBIAS) {
        bb0 = (c0 < 64) ? 0.f : bias[c0 - 64];
        bb1 = (c0 + 16 < 64) ? 0.f : bias[c0 + 16 - 64];
    } else { bb0 = bias[c0]; bb1 = bias[c0 + 16]; }
#pragma unroll
    for (int m = 0; m < 4; ++m) {
#pragma unroll
        for (int r = 0; r < 4; ++r) {
            const int row = m0 + m * 16 + lkb * 4 + r;
            if (row < N_NODES) {
                const float v0 = acc[m][0][r] + bb0;
                const float v1 = acc[m][1][r] + bb1;
                C[(long)row * 128 + c0]      = ACT ? fast_tanh(v0) : v0;
                C[(long)row * 128 + c0 + 16] = ACT ? fast_tanh(v1) : v1;
            }
        }
    }
}

// ---------------------------------------------------------------------------
// CSR build: count -> hierarchical scan -> XCD-localized fill
// ---------------------------------------------------------------------------
__global__ void count_kernel(const int* __restrict__ ei, int* __restrict__ count)
{
    const int e = blockIdx.x * blockDim.x + threadIdx.x;
    if (e < N_EDGES) atomicAdd(&count[ei[N_EDGES + e]], 1);
}

__global__ __launch_bounds__(256)
void scan_blocks_kernel(const int* __restrict__ count, int* __restrict__ blocksum)
{
    __shared__ int red[256];
    const int i = blockIdx.x * 256 + threadIdx.x;
    red[threadIdx.x] = (i < N_NODES) ? count[i] : 0;
    __syncthreads();
#pragma unroll
    for (int d = 128; d > 0; d >>= 1) {
        if (threadIdx.x < d) red[threadIdx.x] += red[threadIdx.x + d];
        __syncthreads();
    }
    if (threadIdx.x == 0) blocksum[blockIdx.x] = red[0];
}

__global__ __launch_bounds__(256)
void scan_base_kernel(const int* __restrict__ blocksum, int* __restrict__ blockbase)
{
    __shared__ int s[256];
    const int t = threadIdx.x;
    const int own = (t < SCAN_B) ? blocksum[t] : 0;
    s[t] = own;
    __syncthreads();
#pragma unroll
    for (int d = 1; d < 256; d <<= 1) {
        const int v = (t >= d) ? s[t - d] : 0;
        __syncthreads();
        s[t] += v;
        __syncthreads();
    }
    if (t < SCAN_B) blockbase[t] = s[t] - own;
}

__global__ __launch_bounds__(256)
void scan_final_kernel(const int* __restrict__ count, const int* __restrict__ blockbase,
                       int* __restrict__ offsets, int* __restrict__ cursor)
{
    __shared__ int s[256];
    const int t = threadIdx.x;
    const int i = blockIdx.x * 256 + t;
    const int v = (i < N_NODES) ? count[i] : 0;
    s[t] = v;
    __syncthreads();
#pragma unroll
    for (int d = 1; d < 256; d <<= 1) {
        const int u = (t >= d) ? s[t - d] : 0;
        __syncthreads();
        s[t] += u;
        __syncthreads();
    }
    if (i < N_NODES) {
        const int off = blockbase[blockIdx.x] + s[t] - v;
        offsets[i] = off;
        cursor[i] = off;
    }
    if (i == 0) offsets[N_NODES] = N_EDGES;
}

// XCD-localized fill: group g = blockIdx%8 handles dst in [g*NPG, (g+1)*NPG);
// packed 8B records -> writes to a group-contiguous CSR region (one XCD's L2).
__global__ __launch_bounds__(256)
void fill_kernel(const int* __restrict__ ei, const float* __restrict__ ew,
                 int* __restrict__ cursor, uint2* __restrict__ rec)
{
    const int g = blockIdx.x & (FILL_GROUPS - 1);
    const int q = blockIdx.x >> 3;
    const int nlo = g * NPG;
    const int nhi = nlo + NPG;
    const int stride = (gridDim.x >> 3) * 256;
    for (int e = q * 256 + threadIdx.x; e < N_EDGES; e += stride) {
        const int t = ei[N_EDGES + e];
        if (t >= nlo && t < nhi) {
            const int pos = atomicAdd(&cursor[t], 1);
            rec[pos] = make_uint2((unsigned)ei[e], __float_as_uint(ew[e]));
        }
    }
}

// ---------------------------------------------------------------------------
// gather aggregation (CSR, packed records): dual accumulators for ILP
// ---------------------------------------------------------------------------
template<int D>
__global__ __launch_bounds__(256)
void gather_agg(const float* __restrict__ feat, int stride,
                const int* __restrict__ offsets, const uint2* __restrict__ rec,
                float* __restrict__ agg)
{
    constexpr int LPN = D / 4;
    constexpr int NPB = 256 / LPN;
    const int lane = threadIdx.x % LPN;
    const int slot = threadIdx.x / LPN;
    const int n = blockIdx.x * NPB + slot;
    if (n >= N_NODES) return;
    const int lo = offsets[n], hi = offsets[n + 1];
    const int j = lane * 4;
    float4 a0 = make_float4(0.f, 0.f, 0.f, 0.f);
    float4 a1 = make_float4(0.f, 0.f, 0.f, 0.f);
    int e = lo;
    for (; e + 1 < hi; e += 2) {
        const uint2 r0 = rec[e];
        const uint2 r1 = rec[e + 1];
        const float4 v0 = *(const float4*)&feat[(long)r0.x * stride + j];
        const float4 v1 = *(const float4*)&feat[(long)r1.x * stride + j];
        const float w0 = __uint_as_float(r0.y);
        const float w1 = __uint_as_float(r1.y);
        a0.x = fmaf(v0.x, w0, a0.x); a0.y = fmaf(v0.y, w0, a0.y);
        a0.z = fmaf(v0.z, w0, a0.z); a0.w = fmaf(v0.w, w0, a0.w);
        a1.x = fmaf(v1.x, w1, a1.x); a1.y = fmaf(v1.y, w1, a1.y);
        a1.z = fmaf(v1.z, w1, a1.z); a1.w = fmaf(v1.w, w1, a1.w);
    }
    if (e < hi) {
        const uint2 r = rec[e];
        const float4 v = *(const float4*)&feat[(long)r.x * stride + j];
        const float w = __uint_as_float(r.y);
        a0.x = fmaf(v.x, w, a0.x); a0.y = fmaf(v.y, w, a0.y);
        a0.z = fmaf(v.z, w, a0.z); a0.w = fmaf(v.w, w, a0.w);
    }
    *(float4*)&agg[(long)n * D + j] =
        make_float4(a0.x + a1.x, a0.y + a1.y, a0.z + a1.z, a0.w + a1.w);
}

// ---------------------------------------------------------------------------
// pool + MLP
// ---------------------------------------------------------------------------
__global__ void gstart_kernel(const int* __restrict__ batch, int* __restrict__ gstart)
{
    const int g = threadIdx.x;
    int lo = 0, hi = N_NODES;
    while (lo < hi) { const int mid = (lo + hi) >> 1; if (batch[mid] < g) lo = mid + 1; else hi = mid; }
    gstart[g] = lo;
    if (g == 0) gstart[N_GRAPHS] = N_NODES;
}

__global__ __launch_bounds__(256)
void pool_seg_kernel(const float* __restrict__ agg3, const float* __restrict__ yr,
                     const int* __restrict__ gstart, float* __restrict__ g)
{
    const int gi = blockIdx.x;
    const int c = threadIdx.x & 63;
    const int sub = threadIdx.x >> 6;
    const int lo = gstart[gi], hi = gstart[gi + 1];
    float acc = 0.f;
    for (int n = lo + sub; n < hi; n += 4)
        acc += fast_tanh(agg3[(long)n * 64 + c] + yr[(long)n * 128 + 64 + c]);
    __shared__ float red[256];
    red[threadIdx.x] = acc;
    __syncthreads();
    if (sub == 0) g[gi * 64 + c] = red[c] + red[64 + c] + red[128 + c] + red[192 + c];
}

__global__ __launch_bounds__(64)
void mlp_kernel(const float* __restrict__ g,
                const float* __restrict__ Wm1, const float* __restrict__ bm1,
                const float* __restrict__ Wm2, const float* __restrict__ bm2,
                const float* __restrict__ Wm3, const float* __restrict__ bm3,
                float* __restrict__ out)
{
    const int gi = blockIdx.x;
    const int l = threadIdx.x;
    __shared__ float gr[64], h1[32], h2[16];
    gr[l] = g[gi * 64 + l];
    __syncthreads();
    if (l < 32) {
        float a = bm1[l];
        const float* w = Wm1 + l * 64;
        for (int k = 0; k < 64; ++k) a = fmaf(gr[k], w[k], a);
        h1[l] = fmaxf(a, 0.f);
    }
    __syncthreads();
    if (l < 16) {
        float a = bm2[l];
        const float* w = Wm2 + l * 32;
        for (int k = 0; k < 32; ++k) a = fmaf(h1[k], w[k], a);
        h2[l] = fmaxf(a, 0.f);
    }
    __syncthreads();
    if (l == 0) {
        float a = bm3[0];
        for (int k = 0; k < 16; ++k) a = fmaf(h2[k], Wm3[k], a);
        out[gi] = a;
    }
}

extern "C" void kernel_launch(void* const* d_in, const int* in_sizes, int n_in,
                              void* d_out, int out_size, void* d_ws, size_t ws_size,
                              hipStream_t stream) {
    const float* x      = (const float*)d_in[0];
    const int*   ei     = (const int*)  d_in[1];
    const int*   batch  = (const int*)  d_in[2];
    const float* ew     = (const float*)d_in[3];
    const float* W1r    = (const float*)d_in[4];
    const float* b1     = (const float*)d_in[5];
    const float* W1root = (const float*)d_in[6];
    const float* W2r    = (const float*)d_in[7];
    const float* b2     = (const float*)d_in[8];
    const float* W2root = (const float*)d_in[9];
    const float* W3r    = (const float*)d_in[10];
    const float* b3     = (const float*)d_in[11];
    const float* W3root = (const float*)d_in[12];
    const float* Wm1    = (const float*)d_in[13];
    const float* bm1    = (const float*)d_in[14];
    const float* Wm2    = (const float*)d_in[15];
    const float* bm2    = (const float*)d_in[16];
    const float* Wm3    = (const float*)d_in[17];
    const float* bm3    = (const float*)d_in[18];
    float* out = (float*)d_out;

    // ---- workspace layout ----
    float* P0   = (float*)d_ws;                   // N*128 f
    float* P1   = P0 + (long)N_NODES * 128;
    float* P2   = P1 + (long)N_NODES * 128;
    float* POOL = P2 + (long)N_NODES * 128;       // 256*64 f
    int*   count    = (int*)(POOL + N_GRAPHS * 64);
    int*   offsets  = count + N_NODES;            // N+1
    int*   cursor   = offsets + N_NODES + 1;      // N+1
    int*   gstart   = cursor + N_NODES + 1;       // 257
    int*   blocksum = gstart + N_GRAPHS + 1;      // SCAN_B
    int*   blockbase= blocksum + SCAN_B;          // SCAN_B
    uintptr_t wp = ((uintptr_t)(blockbase + SCAN_B) + 15) & ~(uintptr_t)15;
    uint2* rec = (uint2*)wp;                      // E * 8B
    unsigned short* Bh1 = (unsigned short*)(rec + N_EDGES);  // 128*128
    unsigned short* Bl1 = Bh1 + 128 * 128;
    unsigned short* Bh2 = Bl1 + 128 * 128;        // 128*256
    unsigned short* Bl2 = Bh2 + 128 * 256;
    unsigned short* Bh3 = Bl2 + 128 * 256;        // 128*128
    unsigned short* Bl3 = Bh3 + 128 * 128;

    const int gemm_grid = (N_NODES + 63) / 64;    // 782
    const int egrid = (N_EDGES + 255) / 256;

    // ---- weight pre-split (bf16 hi/lo) ----
    pack_w_kernel<<<(128 * 128 + 255) / 256, 256, 0, stream>>>(W1r, W1root, 64, 128, 0, Bh1, Bl1);
    pack_w_kernel<<<(128 * 256 + 255) / 256, 256, 0, stream>>>(W2r, W2root, 128, 256, 0, Bh2, Bl2);
    pack_w_kernel<<<(128 * 128 + 255) / 256, 256, 0, stream>>>(W3r, W3root, 128, 128, 1, Bh3, Bl3);

    // ---- CSR build ----
    hipMemsetAsync(count, 0, N_NODES * sizeof(int), stream);
    count_kernel<<<egrid, 256, 0, stream>>>(ei, count);
    scan_blocks_kernel<<<SCAN_B, 256, 0, stream>>>(count, blocksum);
    scan_base_kernel<<<1, 256, 0, stream>>>(blocksum, blockbase);
    scan_final_kernel<<<SCAN_B, 256, 0, stream>>>(count, blockbase, offsets, cursor);
    fill_kernel<<<2048, 256, 0, stream>>>(ei, ew, cursor, rec);
    gstart_kernel<<<1, 256, 0, stream>>>(batch, gstart);

    // ---- layer 1: agg1 (N x 64) in P2; h1 in P1 ----
    gather_agg<64><<<(N_NODES + 15) / 16, 256, 0, stream>>>(x, 64, offsets, rec, P2);
    gemm_mfma<128, true, false, true><<<gemm_grid, 256, 0, stream>>>(P2, x, 64, Bh1, Bl1, b1, P1);

    // ---- layer 2: agg2 (N x 128) in P0; h2 in P2 ----
    gather_agg<128><<<(N_NODES + 7) / 8, 256, 0, stream>>>(P1, 128, offsets, rec, P0);
    gemm_mfma<256, true, false, true><<<gemm_grid, 256, 0, stream>>>(P0, P1, 128, Bh2, Bl2, b2, P2);

    // ---- layer 3: yr (N x 128: [y3 | root3+b3]) in P1; agg3 (N x 64) in P0 ----
    gemm_mfma<128, false, true, false><<<gemm_grid, 256, 0, stream>>>(P2, P2, 128, Bh3, Bl3, b3, P1);
    gather_agg<64><<<(N_NODES + 15) / 16, 256, 0, stream>>>(P1, 128, offsets, rec, P0);

    // ---- pool + MLP ----
    pool_seg_kernel<<<N_GRAPHS, 256, 0, stream>>>(P0, P1, gstart, POOL);
    mlp_kernel<<<N_GRAPHS, 64, 0, stream>>>(POOL, Wm1, bm1, Wm2, bm2, Wm3, bm3, out);
}

// Round 7
// 297.202 us; speedup vs baseline: 10.2672x; 1.0167x over previous
//
#include <hip/hip_runtime.h>

#define N_NODES 50000
#define N_EDGES 800000
#define N_GRAPHS 256
#define SCAN_B ((N_NODES + 255) / 256)
#define FILL_GROUPS 8
#define NPG (N_NODES / FILL_GROUPS)   // 6250 nodes per group

typedef __attribute__((ext_vector_type(8))) short bf16x8;
typedef __attribute__((ext_vector_type(4))) float f32x4;

__device__ inline unsigned short f2bf(float f) {
    unsigned int u = __float_as_uint(f);
    u += 0x7fff + ((u >> 16) & 1);          // RNE
    return (unsigned short)(u >> 16);
}
__device__ inline float bf2f(unsigned short h) {
    return __uint_as_float(((unsigned int)h) << 16);
}
__device__ inline float fast_tanh(float x) {
    return 1.0f - 2.0f / (__expf(2.0f * x) + 1.0f);
}

// ---------------------------------------------------------------------------
// weight pre-split: fp32 -> packed bf16 hi/lo, concatenated [128][KTOT]
// ---------------------------------------------------------------------------
__global__ void pack_w_kernel(const float* __restrict__ s0, const float* __restrict__ s1,
                              int K0, int KTOT, int nconcat,
                              unsigned short* __restrict__ hi, unsigned short* __restrict__ lo)
{
    const int idx = blockIdx.x * 256 + threadIdx.x;
    if (idx >= 128 * KTOT) return;
    const int c = idx / KTOT, k = idx % KTOT;
    float v;
    if (nconcat) v = (c < 64) ? s0[c * KTOT + k] : s1[(c - 64) * KTOT + k];
    else         v = (k < K0) ? s0[c * K0 + k]   : s1[c * K0 + (k - K0)];
    const unsigned short h = f2bf(v);
    hi[idx] = h;
    lo[idx] = f2bf(v - bf2f(h));
}

// ---------------------------------------------------------------------------
// MFMA GEMM: C[m][0:128] = act( [A0|A1][m][0:KTOT] @ Bcat^T + bias )
// bf16x3 split product: ah*bh + al*bh + ah*bl, fp32 accumulate.
// ---------------------------------------------------------------------------
template<int KTOT, bool KSPLIT, bool NBIAS, bool ACT>
__global__ __launch_bounds__(256)
void gemm_mfma(const float* __restrict__ A0, const float* __restrict__ A1, int astr,
               const unsigned short* __restrict__ Bhi, const unsigned short* __restrict__ Blo,
               const float* __restrict__ bias, float* __restrict__ C)
{
    __shared__ __align__(16) unsigned short lah[64 * 40];
    __shared__ __align__(16) unsigned short lal[64 * 40];
    __shared__ __align__(16) unsigned short lbh[128 * 40];
    __shared__ __align__(16) unsigned short lbl[128 * 40];

    const int tid = threadIdx.x;
    const int w = tid >> 6;
    const int lane = tid & 63;
    const int lrow = lane & 15;
    const int lkb = lane >> 4;
    const int m0 = blockIdx.x * 64;

    constexpr int NCH = KTOT / 32;
    f32x4 acc[4][2] = {};

    for (int ch = 0; ch < NCH; ++ch) {
        const float* __restrict__ Asel;
        int ak0;
        if (KSPLIT) {
            Asel = (ch < NCH / 2) ? A0 : A1;
            ak0 = (ch % (NCH / 2)) * 32;
        } else { Asel = A0; ak0 = ch * 32; }
        const int bk0 = ch * 32;

        __syncthreads();
#pragma unroll
        for (int p = 0; p < 2; ++p) {
            const int f = tid + p * 256;
            const int r = f >> 3;
            const int q = f & 7;
            int row = m0 + r; if (row >= N_NODES) row = N_NODES - 1;
            const float4 v = *(const float4*)&Asel[(long)row * astr + ak0 + q * 4];
            const unsigned short h0 = f2bf(v.x), h1 = f2bf(v.y), h2 = f2bf(v.z), h3 = f2bf(v.w);
            *(ushort4*)&lah[r * 40 + q * 4] = make_ushort4(h0, h1, h2, h3);
            *(ushort4*)&lal[r * 40 + q * 4] =
                make_ushort4(f2bf(v.x - bf2f(h0)), f2bf(v.y - bf2f(h1)),
                             f2bf(v.z - bf2f(h2)), f2bf(v.w - bf2f(h3)));
        }
#pragma unroll
        for (int p = 0; p < 2; ++p) {
            const int f = tid + p * 256;
            const int r = f >> 2;
            const int q = f & 3;
            const long g = (long)r * KTOT + bk0 + q * 8;
            *(uint4*)&lbh[r * 40 + q * 8] = *(const uint4*)&Bhi[g];
            *(uint4*)&lbl[r * 40 + q * 8] = *(const uint4*)&Blo[g];
        }
        __syncthreads();

        const int bo0 = (w * 32 + lrow) * 40 + lkb * 8;
        const int bo1 = bo0 + 16 * 40;
        const bf16x8 bh0 = *(const bf16x8*)&lbh[bo0];
        const bf16x8 bh1 = *(const bf16x8*)&lbh[bo1];
        const bf16x8 bl0 = *(const bf16x8*)&lbl[bo0];
        const bf16x8 bl1 = *(const bf16x8*)&lbl[bo1];
#pragma unroll
        for (int m = 0; m < 4; ++m) {
            const int ao = (m * 16 + lrow) * 40 + lkb * 8;
            const bf16x8 ah = *(const bf16x8*)&lah[ao];
            const bf16x8 al = *(const bf16x8*)&lal[ao];
            acc[m][0] = __builtin_amdgcn_mfma_f32_16x16x32_bf16(ah, bh0, acc[m][0], 0, 0, 0);
            acc[m][1] = __builtin_amdgcn_mfma_f32_16x16x32_bf16(ah, bh1, acc[m][1], 0, 0, 0);
            acc[m][0] = __builtin_amdgcn_mfma_f32_16x16x32_bf16(al, bh0, acc[m][0], 0, 0, 0);
            acc[m][1] = __builtin_amdgcn_mfma_f32_16x16x32_bf16(al, bh1, acc[m][1], 0, 0, 0);
            acc[m][0] = __builtin_amdgcn_mfma_f32_16x16x32_bf16(ah, bl0, acc[m][0], 0, 0, 0);
            acc[m][1] = __builtin_amdgcn_mfma_f32_16x16x32_bf16(ah, bl1, acc[m][1], 0, 0, 0);
        }
    }

    const int c0 = w * 32 + lrow;
    float bb0, bb1;
    if (NBIAS) {
        bb0 = (c0 < 64) ? 0.f : bias[c0 - 64];
        bb1 = (c0 + 16 < 64) ? 0.f : bias[c0 + 16 - 64];
    } else { bb0 = bias[c0]; bb1 = bias[c0 + 16]; }
#pragma unroll
    for (int m = 0; m < 4; ++m) {
#pragma unroll
        for (int r = 0; r < 4; ++r) {
            const int row = m0 + m * 16 + lkb * 4 + r;
            if (row < N_NODES) {
                const float v0 = acc[m][0][r] + bb0;
                const float v1 = acc[m][1][r] + bb1;
                C[(long)row * 128 + c0]      = ACT ? fast_tanh(v0) : v0;
                C[(long)row * 128 + c0 + 16] = ACT ? fast_tanh(v1) : v1;
            }
        }
    }
}

// ---------------------------------------------------------------------------
// CSR build: count -> hierarchical scan -> XCD-localized fill
// ---------------------------------------------------------------------------
__global__ void count_kernel(const int* __restrict__ ei, int* __restrict__ count)
{
    const int e = blockIdx.x * blockDim.x + threadIdx.x;
    if (e < N_EDGES) atomicAdd(&count[ei[N_EDGES + e]], 1);
}

__global__ __launch_bounds__(256)
void scan_blocks_kernel(const int* __restrict__ count, int* __restrict__ blocksum)
{
    __shared__ int red[256];
    const int i = blockIdx.x * 256 + threadIdx.x;
    red[threadIdx.x] = (i < N_NODES) ? count[i] : 0;
    __syncthreads();
#pragma unroll
    for (int d = 128; d > 0; d >>= 1) {
        if (threadIdx.x < d) red[threadIdx.x] += red[threadIdx.x + d];
        __syncthreads();
    }
    if (threadIdx.x == 0) blocksum[blockIdx.x] = red[0];
}

__global__ __launch_bounds__(256)
void scan_base_kernel(const int* __restrict__ blocksum, int* __restrict__ blockbase)
{
    __shared__ int s[256];
    const int t = threadIdx.x;
    const int own = (t < SCAN_B) ? blocksum[t] : 0;
    s[t] = own;
    __syncthreads();
#pragma unroll
    for (int d = 1; d < 256; d <<= 1) {
        const int v = (t >= d) ? s[t - d] : 0;
        __syncthreads();
        s[t] += v;
        __syncthreads();
    }
    if (t < SCAN_B) blockbase[t] = s[t] - own;
}

__global__ __launch_bounds__(256)
void scan_final_kernel(const int* __restrict__ count, const int* __restrict__ blockbase,
                       int* __restrict__ offsets, int* __restrict__ cursor)
{
    __shared__ int s[256];
    const int t = threadIdx.x;
    const int i = blockIdx.x * 256 + t;
    const int v = (i < N_NODES) ? count[i] : 0;
    s[t] = v;
    __syncthreads();
#pragma unroll
    for (int d = 1; d < 256; d <<= 1) {
        const int u = (t >= d) ? s[t - d] : 0;
        __syncthreads();
        s[t] += u;
        __syncthreads();
    }
    if (i < N_NODES) {
        const int off = blockbase[blockIdx.x] + s[t] - v;
        offsets[i] = off;
        cursor[i] = off;
    }
    if (i == 0) offsets[N_NODES] = N_EDGES;
}

// XCD-localized fill: group g = blockIdx%8 handles dst in [g*NPG, (g+1)*NPG)
__global__ __launch_bounds__(256)
void fill_kernel(const int* __restrict__ ei, const float* __restrict__ ew,
                 int* __restrict__ cursor, uint2* __restrict__ rec)
{
    const int g = blockIdx.x & (FILL_GROUPS - 1);
    const int q = blockIdx.x >> 3;
    const int nlo = g * NPG;
    const int nhi = nlo + NPG;
    const int stride = (gridDim.x >> 3) * 256;
    for (int e = q * 256 + threadIdx.x; e < N_EDGES; e += stride) {
        const int t = ei[N_EDGES + e];
        if (t >= nlo && t < nhi) {
            const int pos = atomicAdd(&cursor[t], 1);
            rec[pos] = make_uint2((unsigned)ei[e], __float_as_uint(ew[e]));
        }
    }
}

// ---------------------------------------------------------------------------
// gather aggregation (CSR, packed records): 4-way edge unroll for MLP depth
// ---------------------------------------------------------------------------
template<int D>
__global__ __launch_bounds__(256)
void gather_agg(const float* __restrict__ feat, int stride,
                const int* __restrict__ offsets, const uint2* __restrict__ rec,
                float* __restrict__ agg)
{
    constexpr int LPN = D / 4;
    constexpr int NPB = 256 / LPN;
    const int lane = threadIdx.x % LPN;
    const int slot = threadIdx.x / LPN;
    const int n = blockIdx.x * NPB + slot;
    if (n >= N_NODES) return;
    const int lo = offsets[n], hi = offsets[n + 1];
    const int j = lane * 4;
    float4 a0 = make_float4(0.f, 0.f, 0.f, 0.f);
    float4 a1 = make_float4(0.f, 0.f, 0.f, 0.f);
    float4 a2 = make_float4(0.f, 0.f, 0.f, 0.f);
    float4 a3 = make_float4(0.f, 0.f, 0.f, 0.f);
    int e = lo;
    for (; e + 3 < hi; e += 4) {
        const uint2 r0 = rec[e];
        const uint2 r1 = rec[e + 1];
        const uint2 r2 = rec[e + 2];
        const uint2 r3 = rec[e + 3];
        const float4 v0 = *(const float4*)&feat[(long)r0.x * stride + j];
        const float4 v1 = *(const float4*)&feat[(long)r1.x * stride + j];
        const float4 v2 = *(const float4*)&feat[(long)r2.x * stride + j];
        const float4 v3 = *(const float4*)&feat[(long)r3.x * stride + j];
        const float w0 = __uint_as_float(r0.y);
        const float w1 = __uint_as_float(r1.y);
        const float w2 = __uint_as_float(r2.y);
        const float w3 = __uint_as_float(r3.y);
        a0.x = fmaf(v0.x, w0, a0.x); a0.y = fmaf(v0.y, w0, a0.y);
        a0.z = fmaf(v0.z, w0, a0.z); a0.w = fmaf(v0.w, w0, a0.w);
        a1.x = fmaf(v1.x, w1, a1.x); a1.y = fmaf(v1.y, w1, a1.y);
        a1.z = fmaf(v1.z, w1, a1.z); a1.w = fmaf(v1.w, w1, a1.w);
        a2.x = fmaf(v2.x, w2, a2.x); a2.y = fmaf(v2.y, w2, a2.y);
        a2.z = fmaf(v2.z, w2, a2.z); a2.w = fmaf(v2.w, w2, a2.w);
        a3.x = fmaf(v3.x, w3, a3.x); a3.y = fmaf(v3.y, w3, a3.y);
        a3.z = fmaf(v3.z, w3, a3.z); a3.w = fmaf(v3.w, w3, a3.w);
    }
    for (; e < hi; ++e) {
        const uint2 r = rec[e];
        const float4 v = *(const float4*)&feat[(long)r.x * stride + j];
        const float w = __uint_as_float(r.y);
        a0.x = fmaf(v.x, w, a0.x); a0.y = fmaf(v.y, w, a0.y);
        a0.z = fmaf(v.z, w, a0.z); a0.w = fmaf(v.w, w, a0.w);
    }
    *(float4*)&agg[(long)n * D + j] =
        make_float4(a0.x + a1.x + a2.x + a3.x, a0.y + a1.y + a2.y + a3.y,
                    a0.z + a1.z + a2.z + a3.z, a0.w + a1.w + a2.w + a3.w);
}

// ---------------------------------------------------------------------------
// pool + MLP
// ---------------------------------------------------------------------------
__global__ void gstart_kernel(const int* __restrict__ batch, int* __restrict__ gstart)
{
    const int g = threadIdx.x;
    int lo = 0, hi = N_NODES;
    while (lo < hi) { const int mid = (lo + hi) >> 1; if (batch[mid] < g) lo = mid + 1; else hi = mid; }
    gstart[g] = lo;
    if (g == 0) gstart[N_GRAPHS] = N_NODES;
}

__global__ __launch_bounds__(256)
void pool_seg_kernel(const float* __restrict__ agg3, const float* __restrict__ yr,
                     const int* __restrict__ gstart, float* __restrict__ g)
{
    const int gi = blockIdx.x;
    const int c = threadIdx.x & 63;
    const int sub = threadIdx.x >> 6;
    const int lo = gstart[gi], hi = gstart[gi + 1];
    float acc = 0.f;
    for (int n = lo + sub; n < hi; n += 4)
        acc += fast_tanh(agg3[(long)n * 64 + c] + yr[(long)n * 128 + 64 + c]);
    __shared__ float red[256];
    red[threadIdx.x] = acc;
    __syncthreads();
    if (sub == 0) g[gi * 64 + c] = red[c] + red[64 + c] + red[128 + c] + red[192 + c];
}

__global__ __launch_bounds__(64)
void mlp_kernel(const float* __restrict__ g,
                const float* __restrict__ Wm1, const float* __restrict__ bm1,
                const float* __restrict__ Wm2, const float* __restrict__ bm2,
                const float* __restrict__ Wm3, const float* __restrict__ bm3,
                float* __restrict__ out)
{
    const int gi = blockIdx.x;
    const int l = threadIdx.x;
    __shared__ float gr[64], h1[32], h2[16];
    gr[l] = g[gi * 64 + l];
    __syncthreads();
    if (l < 32) {
        float a = bm1[l];
        const float* w = Wm1 + l * 64;
        for (int k = 0; k < 64; ++k) a = fmaf(gr[k], w[k], a);
        h1[l] = fmaxf(a, 0.f);
    }
    __syncthreads();
    if (l < 16) {
        float a = bm2[l];
        const float* w = Wm2 + l * 32;
        for (int k = 0; k < 32; ++k) a = fmaf(h1[k], w[k], a);
        h2[l] = fmaxf(a, 0.f);
    }
    __syncthreads();
    if (l == 0) {
        float a = bm3[0];
        for (int k = 0; k < 16; ++k) a = fmaf(h2[k], Wm3[k], a);
        out[gi] = a;
    }
}

extern "C" void kernel_launch(void* const* d_in, const int* in_sizes, int n_in,
                              void* d_out, int out_size, void* d_ws, size_t ws_size,
                              hipStream_t stream) {
    const float* x      = (const float*)d_in[0];
    const int*   ei     = (const int*)  d_in[1];
    const int*   batch  = (const int*)  d_in[2];
    const float* ew     = (const float*)d_in[3];
    const float* W1r    = (const float*)d_in[4];
    const float* b1     = (const float*)d_in[5];
    const float* W1root = (const float*)d_in[6];
    const float* W2r    = (const float*)d_in[7];
    const float* b2     = (const float*)d_in[8];
    const float* W2root = (const float*)d_in[9];
    const float* W3r    = (const float*)d_in[10];
    const float* b3     = (const float*)d_in[11];
    const float* W3root = (const float*)d_in[12];
    const float* Wm1    = (const float*)d_in[13];
    const float* bm1    = (const float*)d_in[14];
    const float* Wm2    = (const float*)d_in[15];
    const float* bm2    = (const float*)d_in[16];
    const float* Wm3    = (const float*)d_in[17];
    const float* bm3    = (const float*)d_in[18];
    float* out = (float*)d_out;

    // ---- workspace layout ----
    float* P0   = (float*)d_ws;                   // N*128 f
    float* P1   = P0 + (long)N_NODES * 128;
    float* P2   = P1 + (long)N_NODES * 128;
    float* POOL = P2 + (long)N_NODES * 128;       // 256*64 f
    int*   count    = (int*)(POOL + N_GRAPHS * 64);
    int*   offsets  = count + N_NODES;            // N+1
    int*   cursor   = offsets + N_NODES + 1;      // N+1
    int*   gstart   = cursor + N_NODES + 1;       // 257
    int*   blocksum = gstart + N_GRAPHS + 1;      // SCAN_B
    int*   blockbase= blocksum + SCAN_B;          // SCAN_B
    uintptr_t wp = ((uintptr_t)(blockbase + SCAN_B) + 15) & ~(uintptr_t)15;
    uint2* rec = (uint2*)wp;                      // E * 8B
    unsigned short* Bh1 = (unsigned short*)(rec + N_EDGES);  // 128*128
    unsigned short* Bl1 = Bh1 + 128 * 128;
    unsigned short* Bh2 = Bl1 + 128 * 128;        // 128*256
    unsigned short* Bl2 = Bh2 + 128 * 256;
    unsigned short* Bh3 = Bl2 + 128 * 256;        // 128*128
    unsigned short* Bl3 = Bh3 + 128 * 128;

    const int gemm_grid = (N_NODES + 63) / 64;    // 782
    const int egrid = (N_EDGES + 255) / 256;

    // ---- weight pre-split (bf16 hi/lo) ----
    pack_w_kernel<<<(128 * 128 + 255) / 256, 256, 0, stream>>>(W1r, W1root, 64, 128, 0, Bh1, Bl1);
    pack_w_kernel<<<(128 * 256 + 255) / 256, 256, 0, stream>>>(W2r, W2root, 128, 256, 0, Bh2, Bl2);
    pack_w_kernel<<<(128 * 128 + 255) / 256, 256, 0, stream>>>(W3r, W3root, 128, 128, 1, Bh3, Bl3);

    // ---- CSR build ----
    hipMemsetAsync(count, 0, N_NODES * sizeof(int), stream);
    count_kernel<<<egrid, 256, 0, stream>>>(ei, count);
    scan_blocks_kernel<<<SCAN_B, 256, 0, stream>>>(count, blocksum);
    scan_base_kernel<<<1, 256, 0, stream>>>(blocksum, blockbase);
    scan_final_kernel<<<SCAN_B, 256, 0, stream>>>(count, blockbase, offsets, cursor);
    fill_kernel<<<2048, 256, 0, stream>>>(ei, ew, cursor, rec);
    gstart_kernel<<<1, 256, 0, stream>>>(batch, gstart);

    // ---- layer 1: agg1 (N x 64) in P2; h1 in P1 ----
    gather_agg<64><<<(N_NODES + 15) / 16, 256, 0, stream>>>(x, 64, offsets, rec, P2);
    gemm_mfma<128, true, false, true><<<gemm_grid, 256, 0, stream>>>(P2, x, 64, Bh1, Bl1, b1, P1);

    // ---- layer 2: agg2 (N x 128) in P0; h2 in P2 ----
    gather_agg<128><<<(N_NODES + 7) / 8, 256, 0, stream>>>(P1, 128, offsets, rec, P0);
    gemm_mfma<256, true, false, true><<<gemm_grid, 256, 0, stream>>>(P0, P1, 128, Bh2, Bl2, b2, P2);

    // ---- layer 3: yr (N x 128: [y3 | root3+b3]) in P1; agg3 (N x 64) in P0 ----
    gemm_mfma<128, false, true, false><<<gemm_grid, 256, 0, stream>>>(P2, P2, 128, Bh3, Bl3, b3, P1);
    gather_agg<64><<<(N_NODES + 15) / 16, 256, 0, stream>>>(P1, 128, offsets, rec, P0);

    // ---- pool + MLP ----
    pool_seg_kernel<<<N_GRAPHS, 256, 0, stream>>>(P0, P1, gstart, POOL);
    mlp_kernel<<<N_GRAPHS, 64, 0, stream>>>(POOL, Wm1, bm1, Wm2, bm2, Wm3, bm3, out);
}

// Round 8
// 268.713 us; speedup vs baseline: 11.3558x; 1.1060x over previous
//
#include <hip/hip_runtime.h>

#define N_NODES 50000
#define N_EDGES 800000
#define N_GRAPHS 256
#define SCAN_B ((N_NODES + 255) / 256)
#define FILL_GROUPS 8
#define NPG (N_NODES / FILL_GROUPS)   // 6250 nodes per group

typedef __attribute__((ext_vector_type(8))) short bf16x8;
typedef __attribute__((ext_vector_type(4))) float f32x4;

__device__ inline unsigned short f2bf(float f) {
    unsigned int u = __float_as_uint(f);
    u += 0x7fff + ((u >> 16) & 1);          // RNE
    return (unsigned short)(u >> 16);
}
__device__ inline float bf2f(unsigned short h) {
    return __uint_as_float(((unsigned int)h) << 16);
}
__device__ inline float fast_tanh(float x) {
    return 1.0f - 2.0f / (__expf(2.0f * x) + 1.0f);
}

// ---------------------------------------------------------------------------
// weight pre-split: fp32 -> packed bf16 hi/lo, concatenated [128][KTOT]
// ---------------------------------------------------------------------------
__global__ void pack_w_kernel(const float* __restrict__ s0, const float* __restrict__ s1,
                              int K0, int KTOT, int nconcat,
                              unsigned short* __restrict__ hi, unsigned short* __restrict__ lo)
{
    const int idx = blockIdx.x * 256 + threadIdx.x;
    if (idx >= 128 * KTOT) return;
    const int c = idx / KTOT, k = idx % KTOT;
    float v;
    if (nconcat) v = (c < 64) ? s0[c * KTOT + k] : s1[(c - 64) * KTOT + k];
    else         v = (k < K0) ? s0[c * K0 + k]   : s1[c * K0 + (k - K0)];
    const unsigned short h = f2bf(v);
    hi[idx] = h;
    lo[idx] = f2bf(v - bf2f(h));
}

// ---------------------------------------------------------------------------
// fp32 -> bf16 convert (vectorized)
// ---------------------------------------------------------------------------
__global__ void cvt_bf16_kernel(const float* __restrict__ in,
                                unsigned short* __restrict__ out, int n4)
{
    const int i = blockIdx.x * 256 + threadIdx.x;
    if (i >= n4) return;
    const float4 v = ((const float4*)in)[i];
    ((ushort4*)out)[i] = make_ushort4(f2bf(v.x), f2bf(v.y), f2bf(v.z), f2bf(v.w));
}

// ---------------------------------------------------------------------------
// MFMA GEMM, mixed A chunks:
//  - chunks [0, KF32/32): A from Af (fp32, on-the-fly hi/lo split, 3 products)
//  - chunks [KF32/32, ..): A from Ab (exact bf16, 2 products)
// B is pre-split hi/lo [128][KF32+KB16].
// OUTSPLIT=false: C16[N][128] = f2bf(act(acc + bias[c]))
// OUTSPLIT=true : cols 0-63 -> C16[N][64] (no bias/act); cols 64-127 -> Cf[N][64]+bias
// ---------------------------------------------------------------------------
template<int KF32, int KB16, bool OUTSPLIT, bool ACT>
__global__ __launch_bounds__(256)
void gemm_mfma(const float* __restrict__ Af, int fstr,
               const unsigned short* __restrict__ Ab, int bstr,
               const unsigned short* __restrict__ Bhi, const unsigned short* __restrict__ Blo,
               const float* __restrict__ bias,
               unsigned short* __restrict__ C16, float* __restrict__ Cf)
{
    constexpr int KTOT = KF32 + KB16;
    constexpr int NCHF = KF32 / 32;
    constexpr int NCH  = KTOT / 32;

    __shared__ __align__(16) unsigned short lah[64 * 40];
    __shared__ __align__(16) unsigned short lal[64 * 40];
    __shared__ __align__(16) unsigned short lbh[128 * 40];
    __shared__ __align__(16) unsigned short lbl[128 * 40];

    const int tid = threadIdx.x;
    const int w = tid >> 6;
    const int lane = tid & 63;
    const int lrow = lane & 15;
    const int lkb = lane >> 4;
    const int m0 = blockIdx.x * 64;

    f32x4 acc[4][2] = {};

    for (int ch = 0; ch < NCH; ++ch) {
        const bool isF = (ch < NCHF);
        const int bk0 = ch * 32;

        __syncthreads();
        if (isF) {
            const int ak0 = ch * 32;
#pragma unroll
            for (int p = 0; p < 2; ++p) {
                const int f = tid + p * 256;
                const int r = f >> 3;
                const int q = f & 7;
                int row = m0 + r; if (row >= N_NODES) row = N_NODES - 1;
                const float4 v = *(const float4*)&Af[(long)row * fstr + ak0 + q * 4];
                const unsigned short h0 = f2bf(v.x), h1 = f2bf(v.y), h2 = f2bf(v.z), h3 = f2bf(v.w);
                *(ushort4*)&lah[r * 40 + q * 4] = make_ushort4(h0, h1, h2, h3);
                *(ushort4*)&lal[r * 40 + q * 4] =
                    make_ushort4(f2bf(v.x - bf2f(h0)), f2bf(v.y - bf2f(h1)),
                                 f2bf(v.z - bf2f(h2)), f2bf(v.w - bf2f(h3)));
            }
        } else {
            const int ak0 = (ch - NCHF) * 32;
            const int r = tid >> 2;
            const int q = tid & 3;
            int row = m0 + r; if (row >= N_NODES) row = N_NODES - 1;
            *(uint4*)&lah[r * 40 + q * 8] = *(const uint4*)&Ab[(long)row * bstr + ak0 + q * 8];
        }
#pragma unroll
        for (int p = 0; p < 2; ++p) {
            const int f = tid + p * 256;
            const int r = f >> 2;
            const int q = f & 3;
            const long g = (long)r * KTOT + bk0 + q * 8;
            *(uint4*)&lbh[r * 40 + q * 8] = *(const uint4*)&Bhi[g];
            *(uint4*)&lbl[r * 40 + q * 8] = *(const uint4*)&Blo[g];
        }
        __syncthreads();

        const int bo0 = (w * 32 + lrow) * 40 + lkb * 8;
        const int bo1 = bo0 + 16 * 40;
        const bf16x8 bh0 = *(const bf16x8*)&lbh[bo0];
        const bf16x8 bh1 = *(const bf16x8*)&lbh[bo1];
        const bf16x8 bl0 = *(const bf16x8*)&lbl[bo0];
        const bf16x8 bl1 = *(const bf16x8*)&lbl[bo1];
#pragma unroll
        for (int m = 0; m < 4; ++m) {
            const int ao = (m * 16 + lrow) * 40 + lkb * 8;
            const bf16x8 ah = *(const bf16x8*)&lah[ao];
            acc[m][0] = __builtin_amdgcn_mfma_f32_16x16x32_bf16(ah, bh0, acc[m][0], 0, 0, 0);
            acc[m][1] = __builtin_amdgcn_mfma_f32_16x16x32_bf16(ah, bh1, acc[m][1], 0, 0, 0);
            acc[m][0] = __builtin_amdgcn_mfma_f32_16x16x32_bf16(ah, bl0, acc[m][0], 0, 0, 0);
            acc[m][1] = __builtin_amdgcn_mfma_f32_16x16x32_bf16(ah, bl1, acc[m][1], 0, 0, 0);
            if (isF) {
                const bf16x8 al = *(const bf16x8*)&lal[ao];
                acc[m][0] = __builtin_amdgcn_mfma_f32_16x16x32_bf16(al, bh0, acc[m][0], 0, 0, 0);
                acc[m][1] = __builtin_amdgcn_mfma_f32_16x16x32_bf16(al, bh1, acc[m][1], 0, 0, 0);
            }
        }
    }

    const int c0 = w * 32 + lrow;
    if (!OUTSPLIT) {
        const float bb0 = bias[c0], bb1 = bias[c0 + 16];
#pragma unroll
        for (int m = 0; m < 4; ++m) {
#pragma unroll
            for (int r = 0; r < 4; ++r) {
                const int row = m0 + m * 16 + lkb * 4 + r;
                if (row < N_NODES) {
                    float v0 = acc[m][0][r] + bb0;
                    float v1 = acc[m][1][r] + bb1;
                    if (ACT) { v0 = fast_tanh(v0); v1 = fast_tanh(v1); }
                    C16[(long)row * 128 + c0]      = f2bf(v0);
                    C16[(long)row * 128 + c0 + 16] = f2bf(v1);
                }
            }
        }
    } else if (c0 < 64) {
#pragma unroll
        for (int m = 0; m < 4; ++m) {
#pragma unroll
            for (int r = 0; r < 4; ++r) {
                const int row = m0 + m * 16 + lkb * 4 + r;
                if (row < N_NODES) {
                    C16[(long)row * 64 + c0]      = f2bf(acc[m][0][r]);
                    C16[(long)row * 64 + c0 + 16] = f2bf(acc[m][1][r]);
                }
            }
        }
    } else {
        const float bb0 = bias[c0 - 64], bb1 = bias[c0 - 48];
#pragma unroll
        for (int m = 0; m < 4; ++m) {
#pragma unroll
            for (int r = 0; r < 4; ++r) {
                const int row = m0 + m * 16 + lkb * 4 + r;
                if (row < N_NODES) {
                    Cf[(long)row * 64 + c0 - 64] = acc[m][0][r] + bb0;
                    Cf[(long)row * 64 + c0 - 48] = acc[m][1][r] + bb1;
                }
            }
        }
    }
}

// ---------------------------------------------------------------------------
// CSR build: count -> hierarchical scan -> XCD-localized fill
// ---------------------------------------------------------------------------
__global__ void count_kernel(const int* __restrict__ ei, int* __restrict__ count)
{
    const int e = blockIdx.x * blockDim.x + threadIdx.x;
    if (e < N_EDGES) atomicAdd(&count[ei[N_EDGES + e]], 1);
}

__global__ __launch_bounds__(256)
void scan_blocks_kernel(const int* __restrict__ count, int* __restrict__ blocksum)
{
    __shared__ int red[256];
    const int i = blockIdx.x * 256 + threadIdx.x;
    red[threadIdx.x] = (i < N_NODES) ? count[i] : 0;
    __syncthreads();
#pragma unroll
    for (int d = 128; d > 0; d >>= 1) {
        if (threadIdx.x < d) red[threadIdx.x] += red[threadIdx.x + d];
        __syncthreads();
    }
    if (threadIdx.x == 0) blocksum[blockIdx.x] = red[0];
}

__global__ __launch_bounds__(256)
void scan_base_kernel(const int* __restrict__ blocksum, int* __restrict__ blockbase)
{
    __shared__ int s[256];
    const int t = threadIdx.x;
    const int own = (t < SCAN_B) ? blocksum[t] : 0;
    s[t] = own;
    __syncthreads();
#pragma unroll
    for (int d = 1; d < 256; d <<= 1) {
        const int v = (t >= d) ? s[t - d] : 0;
        __syncthreads();
        s[t] += v;
        __syncthreads();
    }
    if (t < SCAN_B) blockbase[t] = s[t] - own;
}

__global__ __launch_bounds__(256)
void scan_final_kernel(const int* __restrict__ count, const int* __restrict__ blockbase,
                       int* __restrict__ offsets, int* __restrict__ cursor)
{
    __shared__ int s[256];
    const int t = threadIdx.x;
    const int i = blockIdx.x * 256 + t;
    const int v = (i < N_NODES) ? count[i] : 0;
    s[t] = v;
    __syncthreads();
#pragma unroll
    for (int d = 1; d < 256; d <<= 1) {
        const int u = (t >= d) ? s[t - d] : 0;
        __syncthreads();
        s[t] += u;
        __syncthreads();
    }
    if (i < N_NODES) {
        const int off = blockbase[blockIdx.x] + s[t] - v;
        offsets[i] = off;
        cursor[i] = off;
    }
    if (i == 0) offsets[N_NODES] = N_EDGES;
}

__global__ __launch_bounds__(256)
void fill_kernel(const int* __restrict__ ei, const float* __restrict__ ew,
                 int* __restrict__ cursor, uint2* __restrict__ rec)
{
    const int g = blockIdx.x & (FILL_GROUPS - 1);
    const int q = blockIdx.x >> 3;
    const int nlo = g * NPG;
    const int nhi = nlo + NPG;
    const int stride = (gridDim.x >> 3) * 256;
    for (int e = q * 256 + threadIdx.x; e < N_EDGES; e += stride) {
        const int t = ei[N_EDGES + e];
        if (t >= nlo && t < nhi) {
            const int pos = atomicAdd(&cursor[t], 1);
            rec[pos] = make_uint2((unsigned)ei[e], __float_as_uint(ew[e]));
        }
    }
}

// ---------------------------------------------------------------------------
// gather aggregation over bf16 features, fp32 accumulate. D/8 lanes per node.
// ---------------------------------------------------------------------------
template<int D>
__global__ __launch_bounds__(256)
void gather_agg(const unsigned short* __restrict__ feat, int stride,
                const int* __restrict__ offsets, const uint2* __restrict__ rec,
                float* __restrict__ agg)
{
    constexpr int LPN = D / 8;
    constexpr int NPB = 256 / LPN;
    const int lane = threadIdx.x % LPN;
    const int slot = threadIdx.x / LPN;
    const int n = blockIdx.x * NPB + slot;
    if (n >= N_NODES) return;
    const int lo = offsets[n], hi = offsets[n + 1];
    const int j = lane * 8;
    float a0[8] = {}, a1[8] = {};
    int e = lo;
    for (; e + 1 < hi; e += 2) {
        const uint2 r0 = rec[e];
        const uint2 r1 = rec[e + 1];
        const bf16x8 v0 = *(const bf16x8*)&feat[(long)r0.x * stride + j];
        const bf16x8 v1 = *(const bf16x8*)&feat[(long)r1.x * stride + j];
        const float w0 = __uint_as_float(r0.y);
        const float w1 = __uint_as_float(r1.y);
#pragma unroll
        for (int k = 0; k < 8; ++k) {
            a0[k] = fmaf(bf2f((unsigned short)v0[k]), w0, a0[k]);
            a1[k] = fmaf(bf2f((unsigned short)v1[k]), w1, a1[k]);
        }
    }
    if (e < hi) {
        const uint2 r = rec[e];
        const bf16x8 v = *(const bf16x8*)&feat[(long)r.x * stride + j];
        const float w = __uint_as_float(r.y);
#pragma unroll
        for (int k = 0; k < 8; ++k)
            a0[k] = fmaf(bf2f((unsigned short)v[k]), w, a0[k]);
    }
    *(float4*)&agg[(long)n * D + j] =
        make_float4(a0[0] + a1[0], a0[1] + a1[1], a0[2] + a1[2], a0[3] + a1[3]);
    *(float4*)&agg[(long)n * D + j + 4] =
        make_float4(a0[4] + a1[4], a0[5] + a1[5], a0[6] + a1[6], a0[7] + a1[7]);
}

// ---------------------------------------------------------------------------
// pool + MLP
// ---------------------------------------------------------------------------
__global__ void gstart_kernel(const int* __restrict__ batch, int* __restrict__ gstart)
{
    const int g = threadIdx.x;
    int lo = 0, hi = N_NODES;
    while (lo < hi) { const int mid = (lo + hi) >> 1; if (batch[mid] < g) lo = mid + 1; else hi = mid; }
    gstart[g] = lo;
    if (g == 0) gstart[N_GRAPHS] = N_NODES;
}

__global__ __launch_bounds__(256)
void pool_seg_kernel(const float* __restrict__ agg3, const float* __restrict__ root3,
                     const int* __restrict__ gstart, float* __restrict__ g)
{
    const int gi = blockIdx.x;
    const int c = threadIdx.x & 63;
    const int sub = threadIdx.x >> 6;
    const int lo = gstart[gi], hi = gstart[gi + 1];
    float acc = 0.f;
    for (int n = lo + sub; n < hi; n += 4)
        acc += fast_tanh(agg3[(long)n * 64 + c] + root3[(long)n * 64 + c]);
    __shared__ float red[256];
    red[threadIdx.x] = acc;
    __syncthreads();
    if (sub == 0) g[gi * 64 + c] = red[c] + red[64 + c] + red[128 + c] + red[192 + c];
}

__global__ __launch_bounds__(64)
void mlp_kernel(const float* __restrict__ g,
                const float* __restrict__ Wm1, const float* __restrict__ bm1,
                const float* __restrict__ Wm2, const float* __restrict__ bm2,
                const float* __restrict__ Wm3, const float* __restrict__ bm3,
                float* __restrict__ out)
{
    const int gi = blockIdx.x;
    const int l = threadIdx.x;
    __shared__ float gr[64], h1[32], h2[16];
    gr[l] = g[gi * 64 + l];
    __syncthreads();
    if (l < 32) {
        float a = bm1[l];
        const float* w = Wm1 + l * 64;
        for (int k = 0; k < 64; ++k) a = fmaf(gr[k], w[k], a);
        h1[l] = fmaxf(a, 0.f);
    }
    __syncthreads();
    if (l < 16) {
        float a = bm2[l];
        const float* w = Wm2 + l * 32;
        for (int k = 0; k < 32; ++k) a = fmaf(h1[k], w[k], a);
        h2[l] = fmaxf(a, 0.f);
    }
    __syncthreads();
    if (l == 0) {
        float a = bm3[0];
        for (int k = 0; k < 16; ++k) a = fmaf(h2[k], Wm3[k], a);
        out[gi] = a;
    }
}

extern "C" void kernel_launch(void* const* d_in, const int* in_sizes, int n_in,
                              void* d_out, int out_size, void* d_ws, size_t ws_size,
                              hipStream_t stream) {
    const float* x      = (const float*)d_in[0];
    const int*   ei     = (const int*)  d_in[1];
    const int*   batch  = (const int*)  d_in[2];
    const float* ew     = (const float*)d_in[3];
    const float* W1r    = (const float*)d_in[4];
    const float* b1     = (const float*)d_in[5];
    const float* W1root = (const float*)d_in[6];
    const float* W2r    = (const float*)d_in[7];
    const float* b2     = (const float*)d_in[8];
    const float* W2root = (const float*)d_in[9];
    const float* W3r    = (const float*)d_in[10];
    const float* b3     = (const float*)d_in[11];
    const float* W3root = (const float*)d_in[12];
    const float* Wm1    = (const float*)d_in[13];
    const float* bm1    = (const float*)d_in[14];
    const float* Wm2    = (const float*)d_in[15];
    const float* bm2    = (const float*)d_in[16];
    const float* Wm3    = (const float*)d_in[17];
    const float* bm3    = (const float*)d_in[18];
    float* out = (float*)d_out;

    // ---- workspace layout ----
    float* agg1  = (float*)d_ws;                        // N*64 f32 (reused as agg3)
    float* agg2  = agg1 + (long)N_NODES * 64;           // N*128 f32 (reused: y3b + root3)
    float* POOL  = agg2 + (long)N_NODES * 128;          // 256*64
    int*   count    = (int*)(POOL + N_GRAPHS * 64);
    int*   offsets  = count + N_NODES;                  // N+1
    int*   cursor   = offsets + N_NODES + 1;            // N+1
    int*   gstart   = cursor + N_NODES + 1;             // 257
    int*   blocksum = gstart + N_GRAPHS + 1;            // SCAN_B
    int*   blockbase= blocksum + SCAN_B;                // SCAN_B
    uintptr_t wp = ((uintptr_t)(blockbase + SCAN_B) + 15) & ~(uintptr_t)15;
    uint2* rec = (uint2*)wp;                            // E * 8B
    unsigned short* xb  = (unsigned short*)(rec + N_EDGES);  // N*64 bf16
    unsigned short* h1b = xb + (long)N_NODES * 64;           // N*128 bf16
    unsigned short* h2b = h1b + (long)N_NODES * 128;         // N*128 bf16
    unsigned short* Bh1 = h2b + (long)N_NODES * 128;         // 128*128
    unsigned short* Bl1 = Bh1 + 128 * 128;
    unsigned short* Bh2 = Bl1 + 128 * 128;                   // 128*256
    unsigned short* Bl2 = Bh2 + 128 * 256;
    unsigned short* Bh3 = Bl2 + 128 * 256;                   // 128*128
    unsigned short* Bl3 = Bh3 + 128 * 128;
    // layer-3 outputs carved from agg2 region (free after GEMM2):
    unsigned short* y3b = (unsigned short*)agg2;             // N*64 bf16
    float* root3 = agg2 + (long)N_NODES * 64;                // N*64 f32
    float* agg3  = agg1;                                     // N*64 f32

    const int gemm_grid = (N_NODES + 63) / 64;    // 782
    const int egrid = (N_EDGES + 255) / 256;

    // ---- weight pre-split + x->bf16 ----
    pack_w_kernel<<<(128 * 128 + 255) / 256, 256, 0, stream>>>(W1r, W1root, 64, 128, 0, Bh1, Bl1);
    pack_w_kernel<<<(128 * 256 + 255) / 256, 256, 0, stream>>>(W2r, W2root, 128, 256, 0, Bh2, Bl2);
    pack_w_kernel<<<(128 * 128 + 255) / 256, 256, 0, stream>>>(W3r, W3root, 128, 128, 1, Bh3, Bl3);
    cvt_bf16_kernel<<<(N_NODES * 64 / 4 + 255) / 256, 256, 0, stream>>>(x, xb, N_NODES * 64 / 4);

    // ---- CSR build ----
    hipMemsetAsync(count, 0, N_NODES * sizeof(int), stream);
    count_kernel<<<egrid, 256, 0, stream>>>(ei, count);
    scan_blocks_kernel<<<SCAN_B, 256, 0, stream>>>(count, blocksum);
    scan_base_kernel<<<1, 256, 0, stream>>>(blocksum, blockbase);
    scan_final_kernel<<<SCAN_B, 256, 0, stream>>>(count, blockbase, offsets, cursor);
    fill_kernel<<<2048, 256, 0, stream>>>(ei, ew, cursor, rec);
    gstart_kernel<<<1, 256, 0, stream>>>(batch, gstart);

    // ---- layer 1: agg1 = gather(xb); h1b = bf16(tanh([agg1|xb]@B1 + b1)) ----
    gather_agg<64><<<(N_NODES + 31) / 32, 256, 0, stream>>>(xb, 64, offsets, rec, agg1);
    gemm_mfma<64, 64, false, true><<<gemm_grid, 256, 0, stream>>>(
        agg1, 64, xb, 64, Bh1, Bl1, b1, h1b, nullptr);

    // ---- layer 2: agg2 = gather(h1b); h2b = bf16(tanh([agg2|h1b]@B2 + b2)) ----
    gather_agg<128><<<(N_NODES + 15) / 16, 256, 0, stream>>>(h1b, 128, offsets, rec, agg2);
    gemm_mfma<128, 128, false, true><<<gemm_grid, 256, 0, stream>>>(
        agg2, 128, h1b, 128, Bh2, Bl2, b2, h2b, nullptr);

    // ---- layer 3: y3b = bf16(h2b@W3r^T); root3 = h2b@W3root^T + b3 ----
    gemm_mfma<0, 128, true, false><<<gemm_grid, 256, 0, stream>>>(
        nullptr, 0, h2b, 128, Bh3, Bl3, b3, y3b, root3);
    gather_agg<64><<<(N_NODES + 31) / 32, 256, 0, stream>>>(y3b, 64, offsets, rec, agg3);

    // ---- pool + MLP ----
    pool_seg_kernel<<<N_GRAPHS, 256, 0, stream>>>(agg3, root3, gstart, POOL);
    mlp_kernel<<<N_GRAPHS, 64, 0, stream>>>(POOL, Wm1, bm1, Wm2, bm2, Wm3, bm3, out);
}